// Round 13
// baseline (343.486 us; speedup 1.0000x reference)
//
#include <hip/hip_runtime.h>
#include <hip/hip_fp16.h>
#include <math.h>

#define N_NODES 50000
#define N_EDGES 1600000
#define D_IN 128
#define D_H 64
#define N_CLS 10
#define N_GRAPHS 64
#define NEG_SLOPE 0.2f
#define E2 (N_EDGES + N_NODES)   // edges + self loops
#define SCAN_BS 256
#define NBLK ((N_NODES + SCAN_BS - 1) / SCAN_BS)   // 196 <= 256

// bucketed scatter params
#define NB 25                 // buckets: dst >> 11 (50000/2048 -> 0..24)
#define BSH 11
#define CAP 76800             // per-bucket staging capacity (>40 sigma over E/NB)
#define HBB 8                 // hist blocks per bucket
#define EPT 8                 // edges/thread in bucket_stage
#define PAD 32                // 128B stride: one cache line per contended counter
#define SLICES 8              // node-slices per bucket in scatter_slice
#define SLICE_W (2048 / SLICES)   // 256 nodes per slice
#define DBINS 128             // degree-sort bins (deg 1..~70 expected)

// packed fp16 via clang ext_vector — plain operators lower to v_pk_*_f16.
// (r5 lesson: ROCm 7.2 hip_fp16.h has NO __hmax2/__hmul2 half2 intrinsics.)
typedef _Float16 f16x2 __attribute__((ext_vector_type(2)));

__device__ inline f16x2 as_h2(unsigned u) { return __builtin_bit_cast(f16x2, u); }
__device__ inline int h2_as_int(f16x2 v) { return __builtin_bit_cast(int, v); }

__device__ inline f16x2 pk_leaky(f16x2 m, f16x2 ns) {
#if __has_builtin(__builtin_elementwise_max)
    return __builtin_elementwise_max(m, m * ns);
#else
    f16x2 p = m * ns, r;
    r.x = m.x > p.x ? m.x : p.x;
    r.y = m.y > p.y ? m.y : p.y;
    return r;
#endif
}

#if __has_builtin(__builtin_amdgcn_fdot2)
__device__ inline float fdot2a(f16x2 a, f16x2 b, float c) {
    return __builtin_amdgcn_fdot2(a, b, c, false);
}
#else
__device__ inline float fdot2a(f16x2 a, f16x2 b, float c) {
    return fmaf((float)a.x, (float)b.x, fmaf((float)a.y, (float)b.y, c));
}
#endif

__device__ inline float wave_reduce_sum(float v) {
    for (int off = 32; off; off >>= 1) v += __shfl_xor(v, off);
    return v;
}

// ===== pass A: bucket-stage edges + eattr sum.
// r0 fix (verified): contended-line atomics were the serializer. esum spread
// over 32 lines, bcursor one line per bucket, EPT=8, int2 staging.
// r4: eattr staged as half2(a,a) so gat's hot loop needs no per-edge cvt.
__global__ void bucket_stage(const int* __restrict__ src, const int* __restrict__ dst,
                             const float* __restrict__ eattr,
                             float* esum, int* bcursor,
                             int2* __restrict__ stg) {
    __shared__ int bcnt[4][32];
    __shared__ int woff[4][32];
    __shared__ float esh[4];
    int t = threadIdx.x;
    int wave = t >> 6;
    if (t < 128) bcnt[t >> 5][t & 31] = 0;
    __syncthreads();
    int e0 = (blockIdx.x * blockDim.x + t) * EPT;   // N_EDGES % EPT == 0
    int ss[EPT], tt[EPT], aa[EPT], r[EPT], b[EPT];
    float v = 0.f;
    bool valid = e0 < N_EDGES;
    if (valid) {
        #pragma unroll
        for (int q = 0; q < EPT / 4; ++q) {
            int4 s4 = *(const int4*)(src + e0 + 4 * q);
            int4 t4 = *(const int4*)(dst + e0 + 4 * q);
            float4 a4 = *(const float4*)(eattr + e0 + 4 * q);
            ss[4*q] = s4.x; ss[4*q+1] = s4.y; ss[4*q+2] = s4.z; ss[4*q+3] = s4.w;
            tt[4*q] = t4.x; tt[4*q+1] = t4.y; tt[4*q+2] = t4.z; tt[4*q+3] = t4.w;
            aa[4*q]   = h2_as_int((f16x2){(_Float16)a4.x, (_Float16)a4.x});
            aa[4*q+1] = h2_as_int((f16x2){(_Float16)a4.y, (_Float16)a4.y});
            aa[4*q+2] = h2_as_int((f16x2){(_Float16)a4.z, (_Float16)a4.z});
            aa[4*q+3] = h2_as_int((f16x2){(_Float16)a4.w, (_Float16)a4.w});
            v += (a4.x + a4.y) + (a4.z + a4.w);
        }
        #pragma unroll
        for (int i = 0; i < EPT; ++i) {
            b[i] = tt[i] >> BSH;
            r[i] = atomicAdd(&bcnt[wave][b[i]], 1);
        }
    }
    v = wave_reduce_sum(v);
    if ((t & 63) == 0) esh[wave] = v;
    __syncthreads();
    if (t < NB) {
        int c0 = bcnt[0][t], c1 = bcnt[1][t], c2 = bcnt[2][t], c3 = bcnt[3][t];
        int tot = c0 + c1 + c2 + c3;
        int base = tot ? atomicAdd(&bcursor[t * PAD], tot) : 0;
        woff[0][t] = base;
        woff[1][t] = base + c0;
        woff[2][t] = base + c0 + c1;
        woff[3][t] = base + c0 + c1 + c2;
    }
    if (t == 0) {
        float tot = (esh[0] + esh[1]) + (esh[2] + esh[3]);
        atomicAdd(&esum[(blockIdx.x & 31) * PAD], tot);   // 32 distinct lines
    }
    __syncthreads();
    if (valid) {
        #pragma unroll
        for (int i = 0; i < EPT; ++i) {
            int p = b[i] * CAP + woff[wave][b[i]] + r[i];
            stg[p] = make_int2((ss[i] & 0xFFFF) | ((tt[i] & 2047) << 16), aa[i]);
        }
    }
}

// ===== pass A2: per-node histogram from staged dst-low bits, LDS-resident window
__global__ void hist_bucket(const int2* __restrict__ stg, const int* __restrict__ bcursor,
                            int* cnt) {
    __shared__ int hist[2048];
    int b = blockIdx.x / HBB;
    int j = blockIdx.x % HBB;
    for (int i = threadIdx.x; i < 2048; i += 256) hist[i] = 0;
    __syncthreads();
    int n = bcursor[b * PAD];
    const int2* sd = stg + (size_t)b * CAP;
    int per = (n + HBB - 1) / HBB;
    int start = j * per;
    int end = min(start + per, n);
    for (int idx = start + threadIdx.x; idx < end; idx += 256)
        atomicAdd(&hist[(sd[idx].x >> 16) & 2047], 1);
    __syncthreads();
    int nb = b << BSH;
    for (int i = threadIdx.x; i < 2048; i += 256) {
        int c = hist[i];
        if (c) atomicAdd(&cnt[nb + i], c);
    }
}

// ---- block-local exclusive scan; +1 per node folds in the self-loop slot ----
__global__ void scan_block(const int* __restrict__ cnt, int* __restrict__ row_start,
                           int* __restrict__ partial) {
    __shared__ int sd[SCAN_BS];
    int i = blockIdx.x * SCAN_BS + threadIdx.x;
    int v = (i < N_NODES) ? (cnt[i] + 1) : 0;   // +1 = self loop
    sd[threadIdx.x] = v;
    __syncthreads();
    for (int off = 1; off < SCAN_BS; off <<= 1) {
        int t = (threadIdx.x >= off) ? sd[threadIdx.x - off] : 0;
        __syncthreads();
        sd[threadIdx.x] += t;
        __syncthreads();
    }
    if (i < N_NODES) row_start[i] = sd[threadIdx.x] - v;
    if (threadIdx.x == SCAN_BS - 1) partial[blockIdx.x] = sd[threadIdx.x];
}
// finalize row_start (redundant LDS scan of partials replaces a launch),
// write self-loop CSR entry (eattr-mean as half2), seed cursor
__global__ void add_offsets(int* __restrict__ row_start, const int* __restrict__ partial,
                            int* __restrict__ cursor, const float* __restrict__ esum,
                            int2* __restrict__ csr_pack) {
    __shared__ int sp[SCAN_BS];
    int pv = (threadIdx.x < NBLK) ? partial[threadIdx.x] : 0;
    sp[threadIdx.x] = pv;
    __syncthreads();
    for (int off = 1; off < SCAN_BS; off <<= 1) {
        int t = (threadIdx.x >= off) ? sp[threadIdx.x - off] : 0;
        __syncthreads();
        sp[threadIdx.x] += t;
        __syncthreads();
    }
    float es = 0.f;
    #pragma unroll
    for (int jj = 0; jj < 32; ++jj) es += esum[jj * PAD];
    float esm = es * (1.0f / N_EDGES);
    int ebits = h2_as_int((f16x2){(_Float16)esm, (_Float16)esm});
    int base = (blockIdx.x == 0) ? 0 : sp[blockIdx.x - 1];
    int i = blockIdx.x * SCAN_BS + threadIdx.x;
    if (i < N_NODES) {
        int r = row_start[i] + base;
        row_start[i] = r;
        csr_pack[r] = make_int2(i, ebits);
        cursor[i] = r + 1;
    }
    if (i == 0) row_start[N_NODES] = E2;
}

// ===== degree-sort (r12): group equal-degree nodes so each gat wave's 8
// nodes share a trip count — removes the ~33% padded-slot waste from
// per-wave max-degree (E[max of 8 Poisson(33)] ~ 44 vs mean 33).
// Three tiny passes over 50K ints; atomic discipline per r0 (one line/bin).
__global__ void deg_hist(const int* __restrict__ row_start, int* __restrict__ dbin) {
    __shared__ int lh[DBINS];
    int t = threadIdx.x;
    for (int i = t; i < DBINS; i += 256) lh[i] = 0;
    __syncthreads();
    int i = blockIdx.x * 256 + t;
    if (i < N_NODES) {
        int d = min(row_start[i + 1] - row_start[i], DBINS - 1);
        atomicAdd(&lh[d], 1);
    }
    __syncthreads();
    for (int j = t; j < DBINS; j += 256) {
        int c = lh[j];
        if (c) atomicAdd(&dbin[j * PAD], c);
    }
}
__global__ void deg_scan(const int* __restrict__ dbin, int* __restrict__ dcur) {
    __shared__ int sd[DBINS];
    int t = threadIdx.x;                    // blockDim = DBINS
    int v = dbin[t * PAD];
    sd[t] = v;
    __syncthreads();
    for (int off = 1; off < DBINS; off <<= 1) {
        int u = (t >= off) ? sd[t - off] : 0;
        __syncthreads();
        sd[t] += u;
        __syncthreads();
    }
    dcur[t * PAD] = sd[t] - v;              // exclusive scan -> bin cursors
}
__global__ void deg_place(const int* __restrict__ row_start, int* __restrict__ dcur,
                          int* __restrict__ order) {
    __shared__ int lh[DBINS];
    __shared__ int lbase[DBINS];
    int t = threadIdx.x;
    for (int i = t; i < DBINS; i += 256) lh[i] = 0;
    __syncthreads();
    int i = blockIdx.x * 256 + t;
    int d = 0, r = 0;
    bool v = i < N_NODES;
    if (v) {
        d = min(row_start[i + 1] - row_start[i], DBINS - 1);
        r = atomicAdd(&lh[d], 1);
    }
    __syncthreads();
    for (int j = t; j < DBINS; j += 256) {
        int c = lh[j];
        lbase[j] = c ? atomicAdd(&dcur[j * PAD], c) : 0;
    }
    __syncthreads();
    if (v) order[lbase[d] + r] = i;
}

// ===== pass B (r3-verified): slice-owned scatter, LDS cursors, deep MLP.
__global__ __launch_bounds__(1024) void scatter_slice(
                              const int2* __restrict__ stg,
                              const int* __restrict__ bcursor,
                              const int* __restrict__ row_start,
                              int2* __restrict__ csr_pack) {
    __shared__ int lcur[SLICE_W];
    int b = blockIdx.x & 31;
    int m = blockIdx.x >> 5;
    if (b >= NB) return;
    int nbase = (b << BSH) + m * SLICE_W;
    for (int i = threadIdx.x; i < SLICE_W; i += 1024) {
        int node = nbase + i;
        lcur[i] = (node < N_NODES) ? row_start[node] + 1 : 0;  // +1 skips self-loop slot
    }
    __syncthreads();
    int n = bcursor[b * PAD];
    const int4* sd4 = (const int4*)(stg + (size_t)b * CAP);   // b*CAP*8B is 16B-aligned
    int n4 = n >> 1;
    int lo = m * SLICE_W, hi = lo + SLICE_W;
    for (int base4 = 0; base4 < n4; base4 += 4096) {
        int4 e[4];
        int idx[4];
        #pragma unroll
        for (int j = 0; j < 4; ++j) {
            idx[j] = base4 + j * 1024 + (int)threadIdx.x;
            if (idx[j] < n4) e[j] = sd4[idx[j]];
        }
        #pragma unroll
        for (int j = 0; j < 4; ++j) {
            if (idx[j] < n4) {
                int dl0 = (e[j].x >> 16) & 2047;
                if (dl0 >= lo && dl0 < hi) {
                    int q = atomicAdd(&lcur[dl0 - lo], 1);
                    csr_pack[q] = make_int2(e[j].x & 0xFFFF, e[j].y);
                }
                int dl1 = (e[j].z >> 16) & 2047;
                if (dl1 >= lo && dl1 < hi) {
                    int q = atomicAdd(&lcur[dl1 - lo], 1);
                    csr_pack[q] = make_int2(e[j].z & 0xFFFF, e[j].w);
                }
            }
        }
    }
    if ((n & 1) && threadIdx.x == 0) {   // odd tail edge; only owning slice stores
        int2 e = stg[(size_t)b * CAP + n - 1];
        int dl = (e.x >> 16) & 2047;
        if (dl >= lo && dl < hi) {
            int q = atomicAdd(&lcur[dl - lo], 1);
            csr_pack[q] = make_int2(e.x & 0xFFFF, e.y);
        }
    }
}

// ---- xl = x@Wl + bl ; xr = x@Wr + br -> fp16 outputs.
// r8/r9-verified LDS-broadcast structure, TN=32, VGPR 32. r11 lesson: manual
// weight prefetch = occupancy tax (compiler already hoists); reverted.
template<int K>
__global__ __launch_bounds__(256) void linear_dual_k(
                              const float* __restrict__ x,
                              const float* __restrict__ Wl, const float* __restrict__ bl,
                              const float* __restrict__ Wr, const float* __restrict__ br,
                              __half* __restrict__ xl, __half* __restrict__ xr) {
    const int TN = 32;            // nodes per block
    const int NPW = TN / 4;       // 8 nodes per wave
    __shared__ float xs[TN * K];  // 16KB (K=128) / 8KB (K=64)
    int t = threadIdx.x;
    int nb = blockIdx.x * TN;
    int rem = N_NODES - nb;
    int tot4 = (rem >= TN ? TN : rem) * (K / 4);
    const float4* xg = (const float4*)(x + (size_t)nb * K);
    float4* xs4 = (float4*)xs;
    for (int i = t; i < tot4; i += 256) xs4[i] = xg[i];
    __syncthreads();
    int wave = t >> 6, d = t & 63;
    int n0 = wave * NPW;
    float blv = bl[d], brv = br[d];
    float al[NPW], ar[NPW];
    #pragma unroll
    for (int i = 0; i < NPW; ++i) { al[i] = blv; ar[i] = brv; }
    #pragma unroll 2
    for (int k4 = 0; k4 < K / 4; ++k4) {
        int kb = k4 * 4;
        float wl[4], wr[4];
        #pragma unroll
        for (int q = 0; q < 4; ++q) {
            wl[q] = Wl[(kb + q) * D_H + d];
            wr[q] = Wr[(kb + q) * D_H + d];
        }
        #pragma unroll
        for (int i = 0; i < NPW; ++i) {
            float4 xv = *(const float4*)&xs[(n0 + i) * K + kb];  // LDS broadcast
            al[i] = fmaf(xv.x, wl[0], al[i]);
            al[i] = fmaf(xv.y, wl[1], al[i]);
            al[i] = fmaf(xv.z, wl[2], al[i]);
            al[i] = fmaf(xv.w, wl[3], al[i]);
            ar[i] = fmaf(xv.x, wr[0], ar[i]);
            ar[i] = fmaf(xv.y, wr[1], ar[i]);
            ar[i] = fmaf(xv.z, wr[2], ar[i]);
            ar[i] = fmaf(xv.w, wr[3], ar[i]);
        }
    }
    #pragma unroll
    for (int i = 0; i < NPW; ++i) {
        int g = nb + n0 + i;
        if (g < N_NODES) {
            xl[(size_t)g * D_H + d] = __float2half(al[i]);
            xr[(size_t)g * D_H + d] = __float2half(ar[i]);
        }
    }
}

// ---- fused GATv2 layer — r9-verified 8-lane-group design (csr-preload
// reverted: r11 showed it cost occupancy for nothing). r12: nodes processed
// in degree-sorted order via order[] so each wave's 8 nodes have ~equal
// trip counts (padded-slot waste ~33% -> ~3%).
__global__ __launch_bounds__(256) void gat_fused(
        const int* __restrict__ row_start, const int2* __restrict__ csr_pack,
        const int* __restrict__ order,
        const __half* __restrict__ xl, const __half* __restrict__ xr,
        const float* __restrict__ We, const float* __restrict__ att,
        const float* __restrict__ b, float* __restrict__ out) {
    int lane = threadIdx.x & 63;
    int g = lane >> 3;                      // 8 groups per wave
    int s = lane & 7;                       // 8 lanes per group
    int wid = blockIdx.x * (blockDim.x >> 6) + (threadIdx.x >> 6);
    int idx = wid * 8 + g;                  // 32 nodes per 256-thread block
    bool nv = idx < N_NODES;
    int node = nv ? order[idx] : 0;
    int fb = s * 8;                         // 8 dims per lane
    float4 wea = *(const float4*)(We + fb), web = *(const float4*)(We + fb + 4);
    float4 ata = *(const float4*)(att + fb), atb = *(const float4*)(att + fb + 4);
    f16x2 we[4] = {{(_Float16)wea.x, (_Float16)wea.y}, {(_Float16)wea.z, (_Float16)wea.w},
                   {(_Float16)web.x, (_Float16)web.y}, {(_Float16)web.z, (_Float16)web.w}};
    f16x2 at[4] = {{(_Float16)ata.x, (_Float16)ata.y}, {(_Float16)ata.z, (_Float16)ata.w},
                   {(_Float16)atb.x, (_Float16)atb.y}, {(_Float16)atb.z, (_Float16)atb.w}};
    int4 xru = *(const int4*)(xr + (size_t)node * D_H + fb);   // 16B, aligned
    f16x2 xr4[4] = {as_h2((unsigned)xru.x), as_h2((unsigned)xru.y),
                    as_h2((unsigned)xru.z), as_h2((unsigned)xru.w)};
    const f16x2 ns = {(_Float16)NEG_SLOPE, (_Float16)NEG_SLOPE};
    int j0 = 0, j1 = 0;
    if (nv) { j0 = row_start[node]; j1 = row_start[node + 1]; }

    float S = 0.f;
    float acc[8] = {0.f, 0.f, 0.f, 0.f, 0.f, 0.f, 0.f, 0.f};

    for (int i0 = j0; i0 < j1; i0 += 4) {   // ~equal trip count across the wave now
        int2 pk[4]; int4 qk[4]; bool vk[4];
        #pragma unroll
        for (int k = 0; k < 4; ++k) {
            vk[k] = (i0 + k) < j1;
            int c = vk[k] ? (i0 + k) : j0;
            pk[k] = csr_pack[c];
        }
        #pragma unroll
        for (int k = 0; k < 4; ++k)
            qk[k] = *(const int4*)(xl + (size_t)pk[k].x * D_H + fb);   // 16B gather
        float t[4];
        #pragma unroll
        for (int k = 0; k < 4; ++k) {
            f16x2 a2 = as_h2((unsigned)pk[k].y);
            f16x2 r0 = as_h2((unsigned)qk[k].x), r1 = as_h2((unsigned)qk[k].y);
            f16x2 r2 = as_h2((unsigned)qk[k].z), r3 = as_h2((unsigned)qk[k].w);
            f16x2 m0 = a2 * we[0] + (r0 + xr4[0]);
            f16x2 m1 = a2 * we[1] + (r1 + xr4[1]);
            f16x2 m2 = a2 * we[2] + (r2 + xr4[2]);
            f16x2 m3 = a2 * we[3] + (r3 + xr4[3]);
            m0 = pk_leaky(m0, ns); m1 = pk_leaky(m1, ns);
            m2 = pk_leaky(m2, ns); m3 = pk_leaky(m3, ns);
            t[k] = fdot2a(m3, at[3], fdot2a(m2, at[2],
                   fdot2a(m1, at[1], fdot2a(m0, at[0], 0.f))));
        }
        #pragma unroll
        for (int off = 1; off <= 4; off <<= 1) {   // reduce within 8-lane group
            t[0] += __shfl_xor(t[0], off);
            t[1] += __shfl_xor(t[1], off);
            t[2] += __shfl_xor(t[2], off);
            t[3] += __shfl_xor(t[3], off);
        }
        #pragma unroll
        for (int k = 0; k < 4; ++k) {
            float z = vk[k] ? __expf(t[k]) : 0.f;
            S += z;
            f16x2 r0 = as_h2((unsigned)qk[k].x), r1 = as_h2((unsigned)qk[k].y);
            f16x2 r2 = as_h2((unsigned)qk[k].z), r3 = as_h2((unsigned)qk[k].w);
            acc[0] = fmaf(z, (float)r0.x, acc[0]);
            acc[1] = fmaf(z, (float)r0.y, acc[1]);
            acc[2] = fmaf(z, (float)r1.x, acc[2]);
            acc[3] = fmaf(z, (float)r1.y, acc[3]);
            acc[4] = fmaf(z, (float)r2.x, acc[4]);
            acc[5] = fmaf(z, (float)r2.y, acc[5]);
            acc[6] = fmaf(z, (float)r3.x, acc[6]);
            acc[7] = fmaf(z, (float)r3.y, acc[7]);
        }
    }

    if (nv) {
        float4 ba = *(const float4*)(b + fb), bb = *(const float4*)(b + fb + 4);
        float bq[8] = {ba.x, ba.y, ba.z, ba.w, bb.x, bb.y, bb.z, bb.w};
        float inv = 1.f / (S + 1e-16f);
        float h[8];
        #pragma unroll
        for (int j = 0; j < 8; ++j) {
            float v = fmaf(acc[j], inv, bq[j]);
            h[j] = v > 0.f ? v : expm1f(v);
        }
        *(float4*)(out + (size_t)node * D_H + fb)     = make_float4(h[0], h[1], h[2], h[3]);
        *(float4*)(out + (size_t)node * D_H + fb + 4) = make_float4(h[4], h[5], h[6], h[7]);
    }
}

// ---- global mean pool (batch is sorted): register accumulate, flush on change.
// r7 (kept): CHUNK=32 — 4x shorter serial dependent-load chain than 128.
__global__ void pool(const float* __restrict__ h, const int* __restrict__ batch,
                     float* __restrict__ pooled, float* __restrict__ counts) {
    const int CHUNK = 32;
    int base = blockIdx.x * CHUNK;
    int d = threadIdx.x;  // blockDim = 64
    float accv = 0.f; int cur_g = -1; int cnt = 0;
    for (int i = 0; i < CHUNK; ++i) {
        int n = base + i;
        if (n >= N_NODES) break;
        int g = batch[n];
        if (g != cur_g) {
            if (cur_g >= 0) {
                atomicAdd(&pooled[cur_g * D_H + d], accv);
                if (d == 0) atomicAdd(&counts[cur_g], (float)cnt);
            }
            cur_g = g; accv = 0.f; cnt = 0;
        }
        accv += h[(size_t)n * D_H + d];
        cnt++;
    }
    if (cur_g >= 0) {
        atomicAdd(&pooled[cur_g * D_H + d], accv);
        if (d == 0) atomicAdd(&counts[cur_g], (float)cnt);
    }
}

__global__ void classify(const float* __restrict__ pooled, const float* __restrict__ counts,
                         const float* __restrict__ Wc, const float* __restrict__ bc,
                         float* __restrict__ out) {
    int tid = threadIdx.x;             // 640 threads
    int g = tid / N_CLS, c = tid % N_CLS;
    if (g >= N_GRAPHS) return;
    float inv = 1.0f / fmaxf(counts[g], 1.0f);
    float a = bc[c];
    for (int k = 0; k < D_H; ++k)
        a = fmaf(pooled[g * D_H + k] * inv, Wc[k * N_CLS + c], a);
    out[g * N_CLS + c] = a;
}

extern "C" void kernel_launch(void* const* d_in, const int* in_sizes, int n_in,
                              void* d_out, int out_size, void* d_ws, size_t ws_size,
                              hipStream_t stream) {
    const float* x     = (const float*)d_in[0];
    const int*   ei    = (const int*)d_in[1];
    const float* eattr = (const float*)d_in[2];
    const int*   batch = (const int*)d_in[3];
    const float *Wl1 = (const float*)d_in[4],  *bl1 = (const float*)d_in[5];
    const float *Wr1 = (const float*)d_in[6],  *br1 = (const float*)d_in[7];
    const float *We1 = (const float*)d_in[8],  *att1 = (const float*)d_in[9];
    const float *b1  = (const float*)d_in[10];
    const float *Wl2 = (const float*)d_in[11], *bl2 = (const float*)d_in[12];
    const float *Wr2 = (const float*)d_in[13], *br2 = (const float*)d_in[14];
    const float *We2 = (const float*)d_in[15], *att2 = (const float*)d_in[16];
    const float *b2  = (const float*)d_in[17];
    const float *Wc  = (const float*)d_in[18], *bc = (const float*)d_in[19];
    float* out = (float*)d_out;

    const int* src = ei;
    const int* dst = ei + N_EDGES;

    // workspace layout. stg (int2, 15.36 MB) is dead after scatter; xl/xr (fp16,
    // 6.4 MB each) + h (fp32, 12.8 MB) = 25.6 MB alias its region. csr_pack kept
    // at the old 30.72 MB offset so it stays clear of xl/xr/h.
    char* base = (char*)d_ws;
    int2*  stg     = (int2*)base;                       // NB*CAP*8B = 15.36 MB
    __half* xl     = (__half*)base;                     // N*64 fp16 (6.4 MB)
    __half* xr     = xl + (size_t)N_NODES * D_H;        // N*64 fp16
    float* h       = (float*)(xr + (size_t)N_NODES * D_H); // N*64 fp32 (12.8 MB)
    int2*  csr_pack = (int2*)(base + (size_t)NB * CAP * 16); // E2 (8B) = 13.2 MB
    int*   row_start = (int*)(csr_pack + E2);           // N+1
    int*   cnt     = row_start + N_NODES + 1;           // N
    float* esum    = (float*)(cnt + N_NODES);           // 32 lines (32*PAD floats)
    int*   bcursor = (int*)(esum + 32 * PAD);           // NB lines (NB*PAD ints)
    int*   cursor  = bcursor + NB * PAD;                // N
    int*   partial = cursor + N_NODES;                  // NBLK
    float* pooled  = (float*)(partial + NBLK);          // 64*64
    float* counts  = pooled + N_GRAPHS * D_H;           // 64
    int*   dbin    = (int*)(counts + N_GRAPHS);         // DBINS lines
    int*   dcur    = dbin + DBINS * PAD;                // DBINS lines
    int*   order   = dcur + DBINS * PAD;                // N

    int gat_blocks = (N_NODES + 31) / 32;               // 32 nodes per 256-thr block
    int lin_blocks = (N_NODES + 31) / 32;               // 32 nodes per block (TN=32)

    hipMemsetAsync(cnt, 0, (N_NODES + 32 * PAD + NB * PAD) * sizeof(int), stream);
    // pooled + counts + dbin zeroed together (contiguous)
    hipMemsetAsync(pooled, 0,
                   (N_GRAPHS * D_H + N_GRAPHS + DBINS * PAD) * sizeof(float), stream);

    // ---- CSR build: stage -> LDS hist -> scan -> slice-scatter ----
    bucket_stage<<<(N_EDGES / EPT + 255) / 256, 256, 0, stream>>>(
        src, dst, eattr, esum, bcursor, stg);
    hist_bucket<<<NB * HBB, 256, 0, stream>>>(stg, bcursor, cnt);
    scan_block<<<NBLK, SCAN_BS, 0, stream>>>(cnt, row_start, partial);
    add_offsets<<<NBLK, SCAN_BS, 0, stream>>>(row_start, partial, cursor, esum, csr_pack);
    // degree-sort (order[]) — needs final row_start
    deg_hist<<<NBLK, 256, 0, stream>>>(row_start, dbin);
    deg_scan<<<1, DBINS, 0, stream>>>(dbin, dcur);
    deg_place<<<NBLK, 256, 0, stream>>>(row_start, dcur, order);
    scatter_slice<<<SLICES * 32, 1024, 0, stream>>>(stg, bcursor, row_start, csr_pack);

    // ---------------- layer 1 ----------------
    linear_dual_k<D_IN><<<lin_blocks, 256, 0, stream>>>(x, Wl1, bl1, Wr1, br1, xl, xr);
    gat_fused<<<gat_blocks, 256, 0, stream>>>(row_start, csr_pack, order, xl, xr, We1, att1, b1, h);

    // ---------------- layer 2 ----------------
    linear_dual_k<D_H><<<lin_blocks, 256, 0, stream>>>(h, Wl2, bl2, Wr2, br2, xl, xr);
    gat_fused<<<gat_blocks, 256, 0, stream>>>(row_start, csr_pack, order, xl, xr, We2, att2, b2, h);

    // ---------------- pool + classify ----------------
    pool<<<(N_NODES + 31) / 32, 64, 0, stream>>>(h, batch, pooled, counts);
    classify<<<1, 640, 0, stream>>>(pooled, counts, Wc, bc, out);
}

// Round 14
// 333.384 us; speedup vs baseline: 1.0303x; 1.0303x over previous
//
#include <hip/hip_runtime.h>
#include <hip/hip_fp16.h>
#include <math.h>

#define N_NODES 50000
#define N_EDGES 1600000
#define D_IN 128
#define D_H 64
#define N_CLS 10
#define N_GRAPHS 64
#define NEG_SLOPE 0.2f
#define E2 (N_EDGES + N_NODES)   // edges + self loops
#define SCAN_BS 256
#define NBLK ((N_NODES + SCAN_BS - 1) / SCAN_BS)   // 196 <= 256

// bucketed scatter params
#define NB 25                 // buckets: dst >> 11 (50000/2048 -> 0..24)
#define BSH 11
#define CAP 76800             // per-bucket staging capacity (>40 sigma over E/NB)
#define HBB 8                 // hist blocks per bucket
#define EPT 8                 // edges/thread in bucket_stage
#define PAD 32                // 128B stride: one cache line per contended counter
#define SLICES 8              // node-slices per bucket in scatter_slice
#define SLICE_W (2048 / SLICES)   // 256 nodes per slice

// packed fp16 via clang ext_vector — plain operators lower to v_pk_*_f16.
// (r5 lesson: ROCm 7.2 hip_fp16.h has NO __hmax2/__hmul2 half2 intrinsics.)
typedef _Float16 f16x2 __attribute__((ext_vector_type(2)));

__device__ inline f16x2 as_h2(unsigned u) { return __builtin_bit_cast(f16x2, u); }
__device__ inline int h2_as_int(f16x2 v) { return __builtin_bit_cast(int, v); }

__device__ inline f16x2 pk_leaky(f16x2 m, f16x2 ns) {
#if __has_builtin(__builtin_elementwise_max)
    return __builtin_elementwise_max(m, m * ns);
#else
    f16x2 p = m * ns, r;
    r.x = m.x > p.x ? m.x : p.x;
    r.y = m.y > p.y ? m.y : p.y;
    return r;
#endif
}

#if __has_builtin(__builtin_amdgcn_fdot2)
__device__ inline float fdot2a(f16x2 a, f16x2 b, float c) {
    return __builtin_amdgcn_fdot2(a, b, c, false);
}
#else
__device__ inline float fdot2a(f16x2 a, f16x2 b, float c) {
    return fmaf((float)a.x, (float)b.x, fmaf((float)a.y, (float)b.y, c));
}
#endif

__device__ inline float wave_reduce_sum(float v) {
    for (int off = 32; off; off >>= 1) v += __shfl_xor(v, off);
    return v;
}

// ===== pass A: bucket-stage edges + eattr sum.
// r0 fix (verified): contended-line atomics were the serializer. esum spread
// over 32 lines, bcursor one line per bucket, EPT=8, int2 staging.
// r4: eattr staged as half2(a,a) so gat's hot loop needs no per-edge cvt.
__global__ void bucket_stage(const int* __restrict__ src, const int* __restrict__ dst,
                             const float* __restrict__ eattr,
                             float* esum, int* bcursor,
                             int2* __restrict__ stg) {
    __shared__ int bcnt[4][32];
    __shared__ int woff[4][32];
    __shared__ float esh[4];
    int t = threadIdx.x;
    int wave = t >> 6;
    if (t < 128) bcnt[t >> 5][t & 31] = 0;
    __syncthreads();
    int e0 = (blockIdx.x * blockDim.x + t) * EPT;   // N_EDGES % EPT == 0
    int ss[EPT], tt[EPT], aa[EPT], r[EPT], b[EPT];
    float v = 0.f;
    bool valid = e0 < N_EDGES;
    if (valid) {
        #pragma unroll
        for (int q = 0; q < EPT / 4; ++q) {
            int4 s4 = *(const int4*)(src + e0 + 4 * q);
            int4 t4 = *(const int4*)(dst + e0 + 4 * q);
            float4 a4 = *(const float4*)(eattr + e0 + 4 * q);
            ss[4*q] = s4.x; ss[4*q+1] = s4.y; ss[4*q+2] = s4.z; ss[4*q+3] = s4.w;
            tt[4*q] = t4.x; tt[4*q+1] = t4.y; tt[4*q+2] = t4.z; tt[4*q+3] = t4.w;
            aa[4*q]   = h2_as_int((f16x2){(_Float16)a4.x, (_Float16)a4.x});
            aa[4*q+1] = h2_as_int((f16x2){(_Float16)a4.y, (_Float16)a4.y});
            aa[4*q+2] = h2_as_int((f16x2){(_Float16)a4.z, (_Float16)a4.z});
            aa[4*q+3] = h2_as_int((f16x2){(_Float16)a4.w, (_Float16)a4.w});
            v += (a4.x + a4.y) + (a4.z + a4.w);
        }
        #pragma unroll
        for (int i = 0; i < EPT; ++i) {
            b[i] = tt[i] >> BSH;
            r[i] = atomicAdd(&bcnt[wave][b[i]], 1);
        }
    }
    v = wave_reduce_sum(v);
    if ((t & 63) == 0) esh[wave] = v;
    __syncthreads();
    if (t < NB) {
        int c0 = bcnt[0][t], c1 = bcnt[1][t], c2 = bcnt[2][t], c3 = bcnt[3][t];
        int tot = c0 + c1 + c2 + c3;
        int base = tot ? atomicAdd(&bcursor[t * PAD], tot) : 0;
        woff[0][t] = base;
        woff[1][t] = base + c0;
        woff[2][t] = base + c0 + c1;
        woff[3][t] = base + c0 + c1 + c2;
    }
    if (t == 0) {
        float tot = (esh[0] + esh[1]) + (esh[2] + esh[3]);
        atomicAdd(&esum[(blockIdx.x & 31) * PAD], tot);   // 32 distinct lines
    }
    __syncthreads();
    if (valid) {
        #pragma unroll
        for (int i = 0; i < EPT; ++i) {
            int p = b[i] * CAP + woff[wave][b[i]] + r[i];
            stg[p] = make_int2((ss[i] & 0xFFFF) | ((tt[i] & 2047) << 16), aa[i]);
        }
    }
}

// ===== pass A2: per-node histogram from staged dst-low bits, LDS-resident window
__global__ void hist_bucket(const int2* __restrict__ stg, const int* __restrict__ bcursor,
                            int* cnt) {
    __shared__ int hist[2048];
    int b = blockIdx.x / HBB;
    int j = blockIdx.x % HBB;
    for (int i = threadIdx.x; i < 2048; i += 256) hist[i] = 0;
    __syncthreads();
    int n = bcursor[b * PAD];
    const int2* sd = stg + (size_t)b * CAP;
    int per = (n + HBB - 1) / HBB;
    int start = j * per;
    int end = min(start + per, n);
    for (int idx = start + threadIdx.x; idx < end; idx += 256)
        atomicAdd(&hist[(sd[idx].x >> 16) & 2047], 1);
    __syncthreads();
    int nb = b << BSH;
    for (int i = threadIdx.x; i < 2048; i += 256) {
        int c = hist[i];
        if (c) atomicAdd(&cnt[nb + i], c);
    }
}

// ---- block-local exclusive scan; +1 per node folds in the self-loop slot ----
__global__ void scan_block(const int* __restrict__ cnt, int* __restrict__ row_start,
                           int* __restrict__ partial) {
    __shared__ int sd[SCAN_BS];
    int i = blockIdx.x * SCAN_BS + threadIdx.x;
    int v = (i < N_NODES) ? (cnt[i] + 1) : 0;   // +1 = self loop
    sd[threadIdx.x] = v;
    __syncthreads();
    for (int off = 1; off < SCAN_BS; off <<= 1) {
        int t = (threadIdx.x >= off) ? sd[threadIdx.x - off] : 0;
        __syncthreads();
        sd[threadIdx.x] += t;
        __syncthreads();
    }
    if (i < N_NODES) row_start[i] = sd[threadIdx.x] - v;
    if (threadIdx.x == SCAN_BS - 1) partial[blockIdx.x] = sd[threadIdx.x];
}
// finalize row_start (redundant LDS scan of partials replaces a launch),
// write self-loop CSR entry (eattr-mean as half2), seed cursor
__global__ void add_offsets(int* __restrict__ row_start, const int* __restrict__ partial,
                            int* __restrict__ cursor, const float* __restrict__ esum,
                            int2* __restrict__ csr_pack) {
    __shared__ int sp[SCAN_BS];
    int pv = (threadIdx.x < NBLK) ? partial[threadIdx.x] : 0;
    sp[threadIdx.x] = pv;
    __syncthreads();
    for (int off = 1; off < SCAN_BS; off <<= 1) {
        int t = (threadIdx.x >= off) ? sp[threadIdx.x - off] : 0;
        __syncthreads();
        sp[threadIdx.x] += t;
        __syncthreads();
    }
    float es = 0.f;
    #pragma unroll
    for (int jj = 0; jj < 32; ++jj) es += esum[jj * PAD];
    float esm = es * (1.0f / N_EDGES);
    int ebits = h2_as_int((f16x2){(_Float16)esm, (_Float16)esm});
    int base = (blockIdx.x == 0) ? 0 : sp[blockIdx.x - 1];
    int i = blockIdx.x * SCAN_BS + threadIdx.x;
    if (i < N_NODES) {
        int r = row_start[i] + base;
        row_start[i] = r;
        csr_pack[r] = make_int2(i, ebits);
        cursor[i] = r + 1;
    }
    if (i == 0) row_start[N_NODES] = E2;
}

// ===== pass B (r3-verified): slice-owned scatter, LDS cursors, deep MLP.
__global__ __launch_bounds__(1024) void scatter_slice(
                              const int2* __restrict__ stg,
                              const int* __restrict__ bcursor,
                              const int* __restrict__ row_start,
                              int2* __restrict__ csr_pack) {
    __shared__ int lcur[SLICE_W];
    int b = blockIdx.x & 31;
    int m = blockIdx.x >> 5;
    if (b >= NB) return;
    int nbase = (b << BSH) + m * SLICE_W;
    for (int i = threadIdx.x; i < SLICE_W; i += 1024) {
        int node = nbase + i;
        lcur[i] = (node < N_NODES) ? row_start[node] + 1 : 0;  // +1 skips self-loop slot
    }
    __syncthreads();
    int n = bcursor[b * PAD];
    const int4* sd4 = (const int4*)(stg + (size_t)b * CAP);   // b*CAP*8B is 16B-aligned
    int n4 = n >> 1;
    int lo = m * SLICE_W, hi = lo + SLICE_W;
    for (int base4 = 0; base4 < n4; base4 += 4096) {
        int4 e[4];
        int idx[4];
        #pragma unroll
        for (int j = 0; j < 4; ++j) {
            idx[j] = base4 + j * 1024 + (int)threadIdx.x;
            if (idx[j] < n4) e[j] = sd4[idx[j]];
        }
        #pragma unroll
        for (int j = 0; j < 4; ++j) {
            if (idx[j] < n4) {
                int dl0 = (e[j].x >> 16) & 2047;
                if (dl0 >= lo && dl0 < hi) {
                    int q = atomicAdd(&lcur[dl0 - lo], 1);
                    csr_pack[q] = make_int2(e[j].x & 0xFFFF, e[j].y);
                }
                int dl1 = (e[j].z >> 16) & 2047;
                if (dl1 >= lo && dl1 < hi) {
                    int q = atomicAdd(&lcur[dl1 - lo], 1);
                    csr_pack[q] = make_int2(e[j].z & 0xFFFF, e[j].w);
                }
            }
        }
    }
    if ((n & 1) && threadIdx.x == 0) {   // odd tail edge; only owning slice stores
        int2 e = stg[(size_t)b * CAP + n - 1];
        int dl = (e.x >> 16) & 2047;
        if (dl >= lo && dl < hi) {
            int q = atomicAdd(&lcur[dl - lo], 1);
            csr_pack[q] = make_int2(e.x & 0xFFFF, e.y);
        }
    }
}

// ---- xl = x@Wl + bl ; xr = x@Wr + br -> fp16 outputs.
// r8/r9-verified: LDS-broadcast structure, TN=32, VGPR 32. Characterized
// limiters: LDS-broadcast issue + weight-load latency; r7 (stream weights),
// r10/r11 (manual prefetch) all regressed — compiler already hoists.
template<int K>
__global__ __launch_bounds__(256) void linear_dual_k(
                              const float* __restrict__ x,
                              const float* __restrict__ Wl, const float* __restrict__ bl,
                              const float* __restrict__ Wr, const float* __restrict__ br,
                              __half* __restrict__ xl, __half* __restrict__ xr) {
    const int TN = 32;            // nodes per block
    const int NPW = TN / 4;       // 8 nodes per wave
    __shared__ float xs[TN * K];  // 16KB (K=128) / 8KB (K=64)
    int t = threadIdx.x;
    int nb = blockIdx.x * TN;
    int rem = N_NODES - nb;
    int tot4 = (rem >= TN ? TN : rem) * (K / 4);
    const float4* xg = (const float4*)(x + (size_t)nb * K);
    float4* xs4 = (float4*)xs;
    for (int i = t; i < tot4; i += 256) xs4[i] = xg[i];
    __syncthreads();
    int wave = t >> 6, d = t & 63;
    int n0 = wave * NPW;
    float blv = bl[d], brv = br[d];
    float al[NPW], ar[NPW];
    #pragma unroll
    for (int i = 0; i < NPW; ++i) { al[i] = blv; ar[i] = brv; }
    #pragma unroll 2
    for (int k4 = 0; k4 < K / 4; ++k4) {
        int kb = k4 * 4;
        float wl[4], wr[4];
        #pragma unroll
        for (int q = 0; q < 4; ++q) {
            wl[q] = Wl[(kb + q) * D_H + d];
            wr[q] = Wr[(kb + q) * D_H + d];
        }
        #pragma unroll
        for (int i = 0; i < NPW; ++i) {
            float4 xv = *(const float4*)&xs[(n0 + i) * K + kb];  // LDS broadcast
            al[i] = fmaf(xv.x, wl[0], al[i]);
            al[i] = fmaf(xv.y, wl[1], al[i]);
            al[i] = fmaf(xv.z, wl[2], al[i]);
            al[i] = fmaf(xv.w, wl[3], al[i]);
            ar[i] = fmaf(xv.x, wr[0], ar[i]);
            ar[i] = fmaf(xv.y, wr[1], ar[i]);
            ar[i] = fmaf(xv.z, wr[2], ar[i]);
            ar[i] = fmaf(xv.w, wr[3], ar[i]);
        }
    }
    #pragma unroll
    for (int i = 0; i < NPW; ++i) {
        int g = nb + n0 + i;
        if (g < N_NODES) {
            xl[(size_t)g * D_H + d] = __float2half(al[i]);
            xr[(size_t)g * D_H + d] = __float2half(ar[i]);
        }
    }
}

// ---- fused GATv2 layer — r9-verified 8-lane-group design (best measured:
// 43.1us/layer). Characterized limiters: random two-level gather at L3
// latency (~50%) + VALU issue (~50%). r10 csr-preload, r12 degree-sort
// both regressed (occupancy tax / locality loss); reverted.
__global__ __launch_bounds__(256) void gat_fused(
        const int* __restrict__ row_start, const int2* __restrict__ csr_pack,
        const __half* __restrict__ xl, const __half* __restrict__ xr,
        const float* __restrict__ We, const float* __restrict__ att,
        const float* __restrict__ b, float* __restrict__ out) {
    int lane = threadIdx.x & 63;
    int g = lane >> 3;                      // 8 groups per wave
    int s = lane & 7;                       // 8 lanes per group
    int wid = blockIdx.x * (blockDim.x >> 6) + (threadIdx.x >> 6);
    int node = wid * 8 + g;                 // 32 nodes per 256-thread block
    bool nv = node < N_NODES;
    int nodec = nv ? node : 0;
    int fb = s * 8;                         // 8 dims per lane
    float4 wea = *(const float4*)(We + fb), web = *(const float4*)(We + fb + 4);
    float4 ata = *(const float4*)(att + fb), atb = *(const float4*)(att + fb + 4);
    f16x2 we[4] = {{(_Float16)wea.x, (_Float16)wea.y}, {(_Float16)wea.z, (_Float16)wea.w},
                   {(_Float16)web.x, (_Float16)web.y}, {(_Float16)web.z, (_Float16)web.w}};
    f16x2 at[4] = {{(_Float16)ata.x, (_Float16)ata.y}, {(_Float16)ata.z, (_Float16)ata.w},
                   {(_Float16)atb.x, (_Float16)atb.y}, {(_Float16)atb.z, (_Float16)atb.w}};
    int4 xru = *(const int4*)(xr + (size_t)nodec * D_H + fb);   // 16B, aligned
    f16x2 xr4[4] = {as_h2((unsigned)xru.x), as_h2((unsigned)xru.y),
                    as_h2((unsigned)xru.z), as_h2((unsigned)xru.w)};
    const f16x2 ns = {(_Float16)NEG_SLOPE, (_Float16)NEG_SLOPE};
    int j0 = 0, j1 = 0;
    if (nv) { j0 = row_start[node]; j1 = row_start[node + 1]; }

    float S = 0.f;
    float acc[8] = {0.f, 0.f, 0.f, 0.f, 0.f, 0.f, 0.f, 0.f};

    for (int i0 = j0; i0 < j1; i0 += 4) {   // same trip count across each 8-lane group
        int2 pk[4]; int4 qk[4]; bool vk[4];
        #pragma unroll
        for (int k = 0; k < 4; ++k) {
            vk[k] = (i0 + k) < j1;
            int c = vk[k] ? (i0 + k) : i0;
            pk[k] = csr_pack[c];
        }
        #pragma unroll
        for (int k = 0; k < 4; ++k)
            qk[k] = *(const int4*)(xl + (size_t)pk[k].x * D_H + fb);   // 16B gather
        float t[4];
        #pragma unroll
        for (int k = 0; k < 4; ++k) {
            f16x2 a2 = as_h2((unsigned)pk[k].y);
            f16x2 r0 = as_h2((unsigned)qk[k].x), r1 = as_h2((unsigned)qk[k].y);
            f16x2 r2 = as_h2((unsigned)qk[k].z), r3 = as_h2((unsigned)qk[k].w);
            f16x2 m0 = a2 * we[0] + (r0 + xr4[0]);
            f16x2 m1 = a2 * we[1] + (r1 + xr4[1]);
            f16x2 m2 = a2 * we[2] + (r2 + xr4[2]);
            f16x2 m3 = a2 * we[3] + (r3 + xr4[3]);
            m0 = pk_leaky(m0, ns); m1 = pk_leaky(m1, ns);
            m2 = pk_leaky(m2, ns); m3 = pk_leaky(m3, ns);
            t[k] = fdot2a(m3, at[3], fdot2a(m2, at[2],
                   fdot2a(m1, at[1], fdot2a(m0, at[0], 0.f))));
        }
        #pragma unroll
        for (int off = 1; off <= 4; off <<= 1) {   // reduce within 8-lane group
            t[0] += __shfl_xor(t[0], off);
            t[1] += __shfl_xor(t[1], off);
            t[2] += __shfl_xor(t[2], off);
            t[3] += __shfl_xor(t[3], off);
        }
        #pragma unroll
        for (int k = 0; k < 4; ++k) {
            float z = vk[k] ? __expf(t[k]) : 0.f;
            S += z;
            f16x2 r0 = as_h2((unsigned)qk[k].x), r1 = as_h2((unsigned)qk[k].y);
            f16x2 r2 = as_h2((unsigned)qk[k].z), r3 = as_h2((unsigned)qk[k].w);
            acc[0] = fmaf(z, (float)r0.x, acc[0]);
            acc[1] = fmaf(z, (float)r0.y, acc[1]);
            acc[2] = fmaf(z, (float)r1.x, acc[2]);
            acc[3] = fmaf(z, (float)r1.y, acc[3]);
            acc[4] = fmaf(z, (float)r2.x, acc[4]);
            acc[5] = fmaf(z, (float)r2.y, acc[5]);
            acc[6] = fmaf(z, (float)r3.x, acc[6]);
            acc[7] = fmaf(z, (float)r3.y, acc[7]);
        }
    }

    if (nv) {
        float4 ba = *(const float4*)(b + fb), bb = *(const float4*)(b + fb + 4);
        float bq[8] = {ba.x, ba.y, ba.z, ba.w, bb.x, bb.y, bb.z, bb.w};
        float inv = 1.f / (S + 1e-16f);
        float h[8];
        #pragma unroll
        for (int j = 0; j < 8; ++j) {
            float v = fmaf(acc[j], inv, bq[j]);
            h[j] = v > 0.f ? v : expm1f(v);
        }
        *(float4*)(out + (size_t)node * D_H + fb)     = make_float4(h[0], h[1], h[2], h[3]);
        *(float4*)(out + (size_t)node * D_H + fb + 4) = make_float4(h[4], h[5], h[6], h[7]);
    }
}

// ---- global mean pool (batch is sorted): register accumulate, flush on change.
// r7 (kept): CHUNK=32 — 4x shorter serial dependent-load chain than 128.
__global__ void pool(const float* __restrict__ h, const int* __restrict__ batch,
                     float* __restrict__ pooled, float* __restrict__ counts) {
    const int CHUNK = 32;
    int base = blockIdx.x * CHUNK;
    int d = threadIdx.x;  // blockDim = 64
    float accv = 0.f; int cur_g = -1; int cnt = 0;
    for (int i = 0; i < CHUNK; ++i) {
        int n = base + i;
        if (n >= N_NODES) break;
        int g = batch[n];
        if (g != cur_g) {
            if (cur_g >= 0) {
                atomicAdd(&pooled[cur_g * D_H + d], accv);
                if (d == 0) atomicAdd(&counts[cur_g], (float)cnt);
            }
            cur_g = g; accv = 0.f; cnt = 0;
        }
        accv += h[(size_t)n * D_H + d];
        cnt++;
    }
    if (cur_g >= 0) {
        atomicAdd(&pooled[cur_g * D_H + d], accv);
        if (d == 0) atomicAdd(&counts[cur_g], (float)cnt);
    }
}

__global__ void classify(const float* __restrict__ pooled, const float* __restrict__ counts,
                         const float* __restrict__ Wc, const float* __restrict__ bc,
                         float* __restrict__ out) {
    int tid = threadIdx.x;             // 640 threads
    int g = tid / N_CLS, c = tid % N_CLS;
    if (g >= N_GRAPHS) return;
    float inv = 1.0f / fmaxf(counts[g], 1.0f);
    float a = bc[c];
    for (int k = 0; k < D_H; ++k)
        a = fmaf(pooled[g * D_H + k] * inv, Wc[k * N_CLS + c], a);
    out[g * N_CLS + c] = a;
}

extern "C" void kernel_launch(void* const* d_in, const int* in_sizes, int n_in,
                              void* d_out, int out_size, void* d_ws, size_t ws_size,
                              hipStream_t stream) {
    const float* x     = (const float*)d_in[0];
    const int*   ei    = (const int*)d_in[1];
    const float* eattr = (const float*)d_in[2];
    const int*   batch = (const int*)d_in[3];
    const float *Wl1 = (const float*)d_in[4],  *bl1 = (const float*)d_in[5];
    const float *Wr1 = (const float*)d_in[6],  *br1 = (const float*)d_in[7];
    const float *We1 = (const float*)d_in[8],  *att1 = (const float*)d_in[9];
    const float *b1  = (const float*)d_in[10];
    const float *Wl2 = (const float*)d_in[11], *bl2 = (const float*)d_in[12];
    const float *Wr2 = (const float*)d_in[13], *br2 = (const float*)d_in[14];
    const float *We2 = (const float*)d_in[15], *att2 = (const float*)d_in[16];
    const float *b2  = (const float*)d_in[17];
    const float *Wc  = (const float*)d_in[18], *bc = (const float*)d_in[19];
    float* out = (float*)d_out;

    const int* src = ei;
    const int* dst = ei + N_EDGES;

    // workspace layout. stg (int2, 15.36 MB) is dead after scatter; xl/xr (fp16,
    // 6.4 MB each) + h (fp32, 12.8 MB) = 25.6 MB alias its region. csr_pack kept
    // at the old 30.72 MB offset so it stays clear of xl/xr/h.
    char* base = (char*)d_ws;
    int2*  stg     = (int2*)base;                       // NB*CAP*8B = 15.36 MB
    __half* xl     = (__half*)base;                     // N*64 fp16 (6.4 MB)
    __half* xr     = xl + (size_t)N_NODES * D_H;        // N*64 fp16
    float* h       = (float*)(xr + (size_t)N_NODES * D_H); // N*64 fp32 (12.8 MB)
    int2*  csr_pack = (int2*)(base + (size_t)NB * CAP * 16); // E2 (8B) = 13.2 MB
    int*   row_start = (int*)(csr_pack + E2);           // N+1
    int*   cnt     = row_start + N_NODES + 1;           // N
    float* esum    = (float*)(cnt + N_NODES);           // 32 lines (32*PAD floats)
    int*   bcursor = (int*)(esum + 32 * PAD);           // NB lines (NB*PAD ints)
    int*   cursor  = bcursor + NB * PAD;                // N
    int*   partial = cursor + N_NODES;                  // NBLK
    float* pooled  = (float*)(partial + NBLK);          // 64*64
    float* counts  = pooled + N_GRAPHS * D_H;           // 64

    int gat_blocks = (N_NODES + 31) / 32;               // 32 nodes per 256-thr block
    int lin_blocks = (N_NODES + 31) / 32;               // 32 nodes per block (TN=32)

    hipMemsetAsync(cnt, 0, (N_NODES + 32 * PAD + NB * PAD) * sizeof(int), stream);
    hipMemsetAsync(pooled, 0, (N_GRAPHS * D_H + N_GRAPHS) * sizeof(float), stream);

    // ---- CSR build: stage -> LDS hist -> scan -> slice-scatter ----
    bucket_stage<<<(N_EDGES / EPT + 255) / 256, 256, 0, stream>>>(
        src, dst, eattr, esum, bcursor, stg);
    hist_bucket<<<NB * HBB, 256, 0, stream>>>(stg, bcursor, cnt);
    scan_block<<<NBLK, SCAN_BS, 0, stream>>>(cnt, row_start, partial);
    add_offsets<<<NBLK, SCAN_BS, 0, stream>>>(row_start, partial, cursor, esum, csr_pack);
    scatter_slice<<<SLICES * 32, 1024, 0, stream>>>(stg, bcursor, row_start, csr_pack);

    // ---------------- layer 1 ----------------
    linear_dual_k<D_IN><<<lin_blocks, 256, 0, stream>>>(x, Wl1, bl1, Wr1, br1, xl, xr);
    gat_fused<<<gat_blocks, 256, 0, stream>>>(row_start, csr_pack, xl, xr, We1, att1, b1, h);

    // ---------------- layer 2 ----------------
    linear_dual_k<D_H><<<lin_blocks, 256, 0, stream>>>(h, Wl2, bl2, Wr2, br2, xl, xr);
    gat_fused<<<gat_blocks, 256, 0, stream>>>(row_start, csr_pack, xl, xr, We2, att2, b2, h);

    // ---------------- pool + classify ----------------
    pool<<<(N_NODES + 31) / 32, 64, 0, stream>>>(h, batch, pooled, counts);
    classify<<<1, 640, 0, stream>>>(pooled, counts, Wc, bc, out);
}

// Round 15
// 307.877 us; speedup vs baseline: 1.1157x; 1.0828x over previous
//
#include <hip/hip_runtime.h>
#include <hip/hip_fp16.h>
#include <math.h>

#define N_NODES 50000
#define N_EDGES 1600000
#define D_IN 128
#define D_H 64
#define N_CLS 10
#define N_GRAPHS 64
#define NEG_SLOPE 0.2f
#define E2 (N_EDGES + N_NODES)   // edges + self loops
#define SCAN_BS 256
#define NBLK ((N_NODES + SCAN_BS - 1) / SCAN_BS)   // 196 <= 256

// bucketed scatter params
#define NB 25                 // buckets: dst >> 11 (50000/2048 -> 0..24)
#define BSH 11
#define CAP 76800             // per-bucket staging capacity (>40 sigma over E/NB)
#define HBB 8                 // hist blocks per bucket
#define EPT 8                 // edges/thread in bucket_stage
#define PAD 32                // 128B stride: one cache line per contended counter
#define SLICES 8              // node-slices per bucket in scatter_slice
#define SLICE_W (2048 / SLICES)   // 256 nodes per slice

// packed fp16 via clang ext_vector — plain operators lower to v_pk_*_f16.
// (r5 lesson: ROCm 7.2 hip_fp16.h has NO __hmax2/__hmul2 half2 intrinsics.)
typedef _Float16 f16x2 __attribute__((ext_vector_type(2)));
typedef _Float16 f16x4 __attribute__((ext_vector_type(4)));
typedef float    fv4   __attribute__((ext_vector_type(4)));

__device__ inline f16x2 as_h2(unsigned u) { return __builtin_bit_cast(f16x2, u); }
__device__ inline int h2_as_int(f16x2 v) { return __builtin_bit_cast(int, v); }

__device__ inline f16x2 pk_leaky(f16x2 m, f16x2 ns) {
#if __has_builtin(__builtin_elementwise_max)
    return __builtin_elementwise_max(m, m * ns);
#else
    f16x2 p = m * ns, r;
    r.x = m.x > p.x ? m.x : p.x;
    r.y = m.y > p.y ? m.y : p.y;
    return r;
#endif
}

#if __has_builtin(__builtin_amdgcn_fdot2)
__device__ inline float fdot2a(f16x2 a, f16x2 b, float c) {
    return __builtin_amdgcn_fdot2(a, b, c, false);
}
#else
__device__ inline float fdot2a(f16x2 a, f16x2 b, float c) {
    return fmaf((float)a.x, (float)b.x, fmaf((float)a.y, (float)b.y, c));
}
#endif

__device__ inline float wave_reduce_sum(float v) {
    for (int off = 32; off; off >>= 1) v += __shfl_xor(v, off);
    return v;
}

// ===== pass A: bucket-stage edges + eattr sum.
// r0 fix (verified): contended-line atomics were the serializer. esum spread
// over 32 lines, bcursor one line per bucket, EPT=8, int2 staging.
// r4: eattr staged as half2(a,a) so gat's hot loop needs no per-edge cvt.
__global__ void bucket_stage(const int* __restrict__ src, const int* __restrict__ dst,
                             const float* __restrict__ eattr,
                             float* esum, int* bcursor,
                             int2* __restrict__ stg) {
    __shared__ int bcnt[4][32];
    __shared__ int woff[4][32];
    __shared__ float esh[4];
    int t = threadIdx.x;
    int wave = t >> 6;
    if (t < 128) bcnt[t >> 5][t & 31] = 0;
    __syncthreads();
    int e0 = (blockIdx.x * blockDim.x + t) * EPT;   // N_EDGES % EPT == 0
    int ss[EPT], tt[EPT], aa[EPT], r[EPT], b[EPT];
    float v = 0.f;
    bool valid = e0 < N_EDGES;
    if (valid) {
        #pragma unroll
        for (int q = 0; q < EPT / 4; ++q) {
            int4 s4 = *(const int4*)(src + e0 + 4 * q);
            int4 t4 = *(const int4*)(dst + e0 + 4 * q);
            float4 a4 = *(const float4*)(eattr + e0 + 4 * q);
            ss[4*q] = s4.x; ss[4*q+1] = s4.y; ss[4*q+2] = s4.z; ss[4*q+3] = s4.w;
            tt[4*q] = t4.x; tt[4*q+1] = t4.y; tt[4*q+2] = t4.z; tt[4*q+3] = t4.w;
            aa[4*q]   = h2_as_int((f16x2){(_Float16)a4.x, (_Float16)a4.x});
            aa[4*q+1] = h2_as_int((f16x2){(_Float16)a4.y, (_Float16)a4.y});
            aa[4*q+2] = h2_as_int((f16x2){(_Float16)a4.z, (_Float16)a4.z});
            aa[4*q+3] = h2_as_int((f16x2){(_Float16)a4.w, (_Float16)a4.w});
            v += (a4.x + a4.y) + (a4.z + a4.w);
        }
        #pragma unroll
        for (int i = 0; i < EPT; ++i) {
            b[i] = tt[i] >> BSH;
            r[i] = atomicAdd(&bcnt[wave][b[i]], 1);
        }
    }
    v = wave_reduce_sum(v);
    if ((t & 63) == 0) esh[wave] = v;
    __syncthreads();
    if (t < NB) {
        int c0 = bcnt[0][t], c1 = bcnt[1][t], c2 = bcnt[2][t], c3 = bcnt[3][t];
        int tot = c0 + c1 + c2 + c3;
        int base = tot ? atomicAdd(&bcursor[t * PAD], tot) : 0;
        woff[0][t] = base;
        woff[1][t] = base + c0;
        woff[2][t] = base + c0 + c1;
        woff[3][t] = base + c0 + c1 + c2;
    }
    if (t == 0) {
        float tot = (esh[0] + esh[1]) + (esh[2] + esh[3]);
        atomicAdd(&esum[(blockIdx.x & 31) * PAD], tot);   // 32 distinct lines
    }
    __syncthreads();
    if (valid) {
        #pragma unroll
        for (int i = 0; i < EPT; ++i) {
            int p = b[i] * CAP + woff[wave][b[i]] + r[i];
            stg[p] = make_int2((ss[i] & 0xFFFF) | ((tt[i] & 2047) << 16), aa[i]);
        }
    }
}

// ===== pass A2: per-node histogram from staged dst-low bits, LDS-resident window
__global__ void hist_bucket(const int2* __restrict__ stg, const int* __restrict__ bcursor,
                            int* cnt) {
    __shared__ int hist[2048];
    int b = blockIdx.x / HBB;
    int j = blockIdx.x % HBB;
    for (int i = threadIdx.x; i < 2048; i += 256) hist[i] = 0;
    __syncthreads();
    int n = bcursor[b * PAD];
    const int2* sd = stg + (size_t)b * CAP;
    int per = (n + HBB - 1) / HBB;
    int start = j * per;
    int end = min(start + per, n);
    for (int idx = start + threadIdx.x; idx < end; idx += 256)
        atomicAdd(&hist[(sd[idx].x >> 16) & 2047], 1);
    __syncthreads();
    int nb = b << BSH;
    for (int i = threadIdx.x; i < 2048; i += 256) {
        int c = hist[i];
        if (c) atomicAdd(&cnt[nb + i], c);
    }
}

// ---- block-local exclusive scan; +1 per node folds in the self-loop slot ----
__global__ void scan_block(const int* __restrict__ cnt, int* __restrict__ row_start,
                           int* __restrict__ partial) {
    __shared__ int sd[SCAN_BS];
    int i = blockIdx.x * SCAN_BS + threadIdx.x;
    int v = (i < N_NODES) ? (cnt[i] + 1) : 0;   // +1 = self loop
    sd[threadIdx.x] = v;
    __syncthreads();
    for (int off = 1; off < SCAN_BS; off <<= 1) {
        int t = (threadIdx.x >= off) ? sd[threadIdx.x - off] : 0;
        __syncthreads();
        sd[threadIdx.x] += t;
        __syncthreads();
    }
    if (i < N_NODES) row_start[i] = sd[threadIdx.x] - v;
    if (threadIdx.x == SCAN_BS - 1) partial[blockIdx.x] = sd[threadIdx.x];
}
// finalize row_start (redundant LDS scan of partials replaces a launch),
// write self-loop CSR entry (eattr-mean as half2), seed cursor
__global__ void add_offsets(int* __restrict__ row_start, const int* __restrict__ partial,
                            int* __restrict__ cursor, const float* __restrict__ esum,
                            int2* __restrict__ csr_pack) {
    __shared__ int sp[SCAN_BS];
    int pv = (threadIdx.x < NBLK) ? partial[threadIdx.x] : 0;
    sp[threadIdx.x] = pv;
    __syncthreads();
    for (int off = 1; off < SCAN_BS; off <<= 1) {
        int t = (threadIdx.x >= off) ? sp[threadIdx.x - off] : 0;
        __syncthreads();
        sp[threadIdx.x] += t;
        __syncthreads();
    }
    float es = 0.f;
    #pragma unroll
    for (int jj = 0; jj < 32; ++jj) es += esum[jj * PAD];
    float esm = es * (1.0f / N_EDGES);
    int ebits = h2_as_int((f16x2){(_Float16)esm, (_Float16)esm});
    int base = (blockIdx.x == 0) ? 0 : sp[blockIdx.x - 1];
    int i = blockIdx.x * SCAN_BS + threadIdx.x;
    if (i < N_NODES) {
        int r = row_start[i] + base;
        row_start[i] = r;
        csr_pack[r] = make_int2(i, ebits);
        cursor[i] = r + 1;
    }
    if (i == 0) row_start[N_NODES] = E2;
}

// ===== pass B (r3-verified): slice-owned scatter, LDS cursors, deep MLP.
__global__ __launch_bounds__(1024) void scatter_slice(
                              const int2* __restrict__ stg,
                              const int* __restrict__ bcursor,
                              const int* __restrict__ row_start,
                              int2* __restrict__ csr_pack) {
    __shared__ int lcur[SLICE_W];
    int b = blockIdx.x & 31;
    int m = blockIdx.x >> 5;
    if (b >= NB) return;
    int nbase = (b << BSH) + m * SLICE_W;
    for (int i = threadIdx.x; i < SLICE_W; i += 1024) {
        int node = nbase + i;
        lcur[i] = (node < N_NODES) ? row_start[node] + 1 : 0;  // +1 skips self-loop slot
    }
    __syncthreads();
    int n = bcursor[b * PAD];
    const int4* sd4 = (const int4*)(stg + (size_t)b * CAP);   // b*CAP*8B is 16B-aligned
    int n4 = n >> 1;
    int lo = m * SLICE_W, hi = lo + SLICE_W;
    for (int base4 = 0; base4 < n4; base4 += 4096) {
        int4 e[4];
        int idx[4];
        #pragma unroll
        for (int j = 0; j < 4; ++j) {
            idx[j] = base4 + j * 1024 + (int)threadIdx.x;
            if (idx[j] < n4) e[j] = sd4[idx[j]];
        }
        #pragma unroll
        for (int j = 0; j < 4; ++j) {
            if (idx[j] < n4) {
                int dl0 = (e[j].x >> 16) & 2047;
                if (dl0 >= lo && dl0 < hi) {
                    int q = atomicAdd(&lcur[dl0 - lo], 1);
                    csr_pack[q] = make_int2(e[j].x & 0xFFFF, e[j].y);
                }
                int dl1 = (e[j].z >> 16) & 2047;
                if (dl1 >= lo && dl1 < hi) {
                    int q = atomicAdd(&lcur[dl1 - lo], 1);
                    csr_pack[q] = make_int2(e[j].z & 0xFFFF, e[j].w);
                }
            }
        }
    }
    if ((n & 1) && threadIdx.x == 0) {   // odd tail edge; only owning slice stores
        int2 e = stg[(size_t)b * CAP + n - 1];
        int dl = (e.x >> 16) & 2047;
        if (dl >= lo && dl < hi) {
            int q = atomicAdd(&lcur[dl - lo], 1);
            csr_pack[q] = make_int2(e.x & 0xFFFF, e.y);
        }
    }
}

// ---- r14: MFMA dual-linear. O[50000x128] = X @ [Wl|Wr] + [bl|br] via
// v_mfma_f32_16x16x16_f16 (carried-forward shape, classic layout:
// a[j]=A[l&15][4(l>>4)+j], b[j]=B[4(l>>4)+j][l&15], d[j]=D[4(l>>4)+j][l&15];
// D mapping matches m89-verified). Operands SWAPPED (A=W^T tile, B=X^T tile)
// so each lane's d[j] = 4 consecutive c of ONE node -> aligned 8B stores.
// fp32 accumulate; fp16 only at inputs/outputs. LDS: X tile fp16 + W
// transposed fp16 (stride K+4: conflict-free b64 reads, 8B-aligned).
// Old vector-ALU version was 43.8us at 42% VALUBusy vs 11us FMA floor —
// G10: matmul-shaped compute belongs on the matrix cores.
template<int K>
__global__ __launch_bounds__(256) void linear_dual_mfma(
        const float* __restrict__ x,
        const float* __restrict__ Wl, const float* __restrict__ bl,
        const float* __restrict__ Wr, const float* __restrict__ br,
        __half* __restrict__ xl, __half* __restrict__ xr) {
    const int KS = K + 4;                    // padded LDS stride (f16 units)
    __shared__ _Float16 Xh[64 * KS];         // 64 nodes x K
    __shared__ _Float16 Wt[128 * KS];        // Wt[c][k]; c<64: Wl, c>=64: Wr
    int t = threadIdx.x;
    int nb = blockIdx.x * 64;
    // stage X (fp32 -> fp16), zero-fill invalid rows
    for (int i = t; i < 64 * (K / 4); i += 256) {
        int n = i / (K / 4), k0 = (i % (K / 4)) * 4;
        float4 v = (nb + n < N_NODES) ? *(const float4*)(x + (size_t)(nb + n) * K + k0)
                                      : make_float4(0.f, 0.f, 0.f, 0.f);
        f16x4 h = {(_Float16)v.x, (_Float16)v.y, (_Float16)v.z, (_Float16)v.w};
        *(f16x4*)&Xh[n * KS + k0] = h;
    }
    // stage W transposed (coalesced reads, scattered u16 LDS writes)
    for (int i = t; i < K * 64; i += 256) {
        int k = i >> 6, c = i & 63;
        Wt[c * KS + k] = (_Float16)Wl[i];
    }
    for (int i = t; i < K * 64; i += 256) {
        int k = i >> 6, c = i & 63;
        Wt[(c + 64) * KS + k] = (_Float16)Wr[i];
    }
    __syncthreads();

    int w = t >> 6, lane = t & 63;
    int np = lane & 15;                      // node within wave tile (B col / D col)
    int g  = lane >> 4;                      // quad index
    int node = nb + w * 16 + np;
    const _Float16* xrow = &Xh[(w * 16 + np) * KS];
    fv4 acc0 = {0.f,0.f,0.f,0.f}, acc1 = {0.f,0.f,0.f,0.f};
    fv4 acc2 = {0.f,0.f,0.f,0.f}, acc3 = {0.f,0.f,0.f,0.f};
    fv4 acc4 = {0.f,0.f,0.f,0.f}, acc5 = {0.f,0.f,0.f,0.f};
    fv4 acc6 = {0.f,0.f,0.f,0.f}, acc7 = {0.f,0.f,0.f,0.f};

#if __has_builtin(__builtin_amdgcn_mfma_f32_16x16x16f16)
    for (int k0 = 0; k0 < K; k0 += 16) {
        f16x4 bf = *(const f16x4*)&xrow[k0 + 4 * g];                 // B = X^T frag
        f16x4 a0 = *(const f16x4*)&Wt[(0 * 16 + np) * KS + k0 + 4 * g];
        f16x4 a1 = *(const f16x4*)&Wt[(1 * 16 + np) * KS + k0 + 4 * g];
        f16x4 a2 = *(const f16x4*)&Wt[(2 * 16 + np) * KS + k0 + 4 * g];
        f16x4 a3 = *(const f16x4*)&Wt[(3 * 16 + np) * KS + k0 + 4 * g];
        f16x4 a4 = *(const f16x4*)&Wt[(4 * 16 + np) * KS + k0 + 4 * g];
        f16x4 a5 = *(const f16x4*)&Wt[(5 * 16 + np) * KS + k0 + 4 * g];
        f16x4 a6 = *(const f16x4*)&Wt[(6 * 16 + np) * KS + k0 + 4 * g];
        f16x4 a7 = *(const f16x4*)&Wt[(7 * 16 + np) * KS + k0 + 4 * g];
        acc0 = __builtin_amdgcn_mfma_f32_16x16x16f16(a0, bf, acc0, 0, 0, 0);
        acc1 = __builtin_amdgcn_mfma_f32_16x16x16f16(a1, bf, acc1, 0, 0, 0);
        acc2 = __builtin_amdgcn_mfma_f32_16x16x16f16(a2, bf, acc2, 0, 0, 0);
        acc3 = __builtin_amdgcn_mfma_f32_16x16x16f16(a3, bf, acc3, 0, 0, 0);
        acc4 = __builtin_amdgcn_mfma_f32_16x16x16f16(a4, bf, acc4, 0, 0, 0);
        acc5 = __builtin_amdgcn_mfma_f32_16x16x16f16(a5, bf, acc5, 0, 0, 0);
        acc6 = __builtin_amdgcn_mfma_f32_16x16x16f16(a6, bf, acc6, 0, 0, 0);
        acc7 = __builtin_amdgcn_mfma_f32_16x16x16f16(a7, bf, acc7, 0, 0, 0);
    }
#else
    // scalar fallback, bit-equivalent lane->element mapping (slow, correct)
    {
        fv4* accs[8] = {&acc0,&acc1,&acc2,&acc3,&acc4,&acc5,&acc6,&acc7};
        for (int ct = 0; ct < 8; ++ct)
            for (int j = 0; j < 4; ++j) {
                float s = 0.f;
                const _Float16* wrow = &Wt[(ct * 16 + 4 * g + j) * KS];
                for (int k = 0; k < K; ++k) s += (float)wrow[k] * (float)xrow[k];
                (*accs[ct])[j] = s;
            }
    }
#endif

    // epilogue: lane holds c = 16*ct + 4*g + j for node `node`
    if (node < N_NODES) {
        #define EMIT(CT, ACC)                                                        \
        {                                                                            \
            const float* bp = ((CT) < 4) ? (bl + (CT) * 16 + 4 * g)                  \
                                         : (br + ((CT) - 4) * 16 + 4 * g);           \
            float4 bv = *(const float4*)bp;                                          \
            f16x4 o = {(_Float16)(ACC[0] + bv.x), (_Float16)(ACC[1] + bv.y),         \
                       (_Float16)(ACC[2] + bv.z), (_Float16)(ACC[3] + bv.w)};        \
            __half* dst = ((CT) < 4)                                                 \
                ? (xl + (size_t)node * D_H + (CT) * 16 + 4 * g)                      \
                : (xr + (size_t)node * D_H + ((CT) - 4) * 16 + 4 * g);               \
            *(f16x4*)dst = o;                                                        \
        }
        EMIT(0, acc0) EMIT(1, acc1) EMIT(2, acc2) EMIT(3, acc3)
        EMIT(4, acc4) EMIT(5, acc5) EMIT(6, acc6) EMIT(7, acc7)
        #undef EMIT
    }
}

// ---- fused GATv2 layer — r9-verified 8-lane-group design (best measured:
// 43.1us/layer). Characterized limiters: random two-level gather at L3
// latency (~50%) + VALU issue (~50%). r10 csr-preload, r12 degree-sort
// both regressed (occupancy tax / locality loss); reverted.
__global__ __launch_bounds__(256) void gat_fused(
        const int* __restrict__ row_start, const int2* __restrict__ csr_pack,
        const __half* __restrict__ xl, const __half* __restrict__ xr,
        const float* __restrict__ We, const float* __restrict__ att,
        const float* __restrict__ b, float* __restrict__ out) {
    int lane = threadIdx.x & 63;
    int g = lane >> 3;                      // 8 groups per wave
    int s = lane & 7;                       // 8 lanes per group
    int wid = blockIdx.x * (blockDim.x >> 6) + (threadIdx.x >> 6);
    int node = wid * 8 + g;                 // 32 nodes per 256-thread block
    bool nv = node < N_NODES;
    int nodec = nv ? node : 0;
    int fb = s * 8;                         // 8 dims per lane
    float4 wea = *(const float4*)(We + fb), web = *(const float4*)(We + fb + 4);
    float4 ata = *(const float4*)(att + fb), atb = *(const float4*)(att + fb + 4);
    f16x2 we[4] = {{(_Float16)wea.x, (_Float16)wea.y}, {(_Float16)wea.z, (_Float16)wea.w},
                   {(_Float16)web.x, (_Float16)web.y}, {(_Float16)web.z, (_Float16)web.w}};
    f16x2 at[4] = {{(_Float16)ata.x, (_Float16)ata.y}, {(_Float16)ata.z, (_Float16)ata.w},
                   {(_Float16)atb.x, (_Float16)atb.y}, {(_Float16)atb.z, (_Float16)atb.w}};
    int4 xru = *(const int4*)(xr + (size_t)nodec * D_H + fb);   // 16B, aligned
    f16x2 xr4[4] = {as_h2((unsigned)xru.x), as_h2((unsigned)xru.y),
                    as_h2((unsigned)xru.z), as_h2((unsigned)xru.w)};
    const f16x2 ns = {(_Float16)NEG_SLOPE, (_Float16)NEG_SLOPE};
    int j0 = 0, j1 = 0;
    if (nv) { j0 = row_start[node]; j1 = row_start[node + 1]; }

    float S = 0.f;
    float acc[8] = {0.f, 0.f, 0.f, 0.f, 0.f, 0.f, 0.f, 0.f};

    for (int i0 = j0; i0 < j1; i0 += 4) {   // same trip count across each 8-lane group
        int2 pk[4]; int4 qk[4]; bool vk[4];
        #pragma unroll
        for (int k = 0; k < 4; ++k) {
            vk[k] = (i0 + k) < j1;
            int c = vk[k] ? (i0 + k) : i0;
            pk[k] = csr_pack[c];
        }
        #pragma unroll
        for (int k = 0; k < 4; ++k)
            qk[k] = *(const int4*)(xl + (size_t)pk[k].x * D_H + fb);   // 16B gather
        float t[4];
        #pragma unroll
        for (int k = 0; k < 4; ++k) {
            f16x2 a2 = as_h2((unsigned)pk[k].y);
            f16x2 r0 = as_h2((unsigned)qk[k].x), r1 = as_h2((unsigned)qk[k].y);
            f16x2 r2 = as_h2((unsigned)qk[k].z), r3 = as_h2((unsigned)qk[k].w);
            f16x2 m0 = a2 * we[0] + (r0 + xr4[0]);
            f16x2 m1 = a2 * we[1] + (r1 + xr4[1]);
            f16x2 m2 = a2 * we[2] + (r2 + xr4[2]);
            f16x2 m3 = a2 * we[3] + (r3 + xr4[3]);
            m0 = pk_leaky(m0, ns); m1 = pk_leaky(m1, ns);
            m2 = pk_leaky(m2, ns); m3 = pk_leaky(m3, ns);
            t[k] = fdot2a(m3, at[3], fdot2a(m2, at[2],
                   fdot2a(m1, at[1], fdot2a(m0, at[0], 0.f))));
        }
        #pragma unroll
        for (int off = 1; off <= 4; off <<= 1) {   // reduce within 8-lane group
            t[0] += __shfl_xor(t[0], off);
            t[1] += __shfl_xor(t[1], off);
            t[2] += __shfl_xor(t[2], off);
            t[3] += __shfl_xor(t[3], off);
        }
        #pragma unroll
        for (int k = 0; k < 4; ++k) {
            float z = vk[k] ? __expf(t[k]) : 0.f;
            S += z;
            f16x2 r0 = as_h2((unsigned)qk[k].x), r1 = as_h2((unsigned)qk[k].y);
            f16x2 r2 = as_h2((unsigned)qk[k].z), r3 = as_h2((unsigned)qk[k].w);
            acc[0] = fmaf(z, (float)r0.x, acc[0]);
            acc[1] = fmaf(z, (float)r0.y, acc[1]);
            acc[2] = fmaf(z, (float)r1.x, acc[2]);
            acc[3] = fmaf(z, (float)r1.y, acc[3]);
            acc[4] = fmaf(z, (float)r2.x, acc[4]);
            acc[5] = fmaf(z, (float)r2.y, acc[5]);
            acc[6] = fmaf(z, (float)r3.x, acc[6]);
            acc[7] = fmaf(z, (float)r3.y, acc[7]);
        }
    }

    if (nv) {
        float4 ba = *(const float4*)(b + fb), bb = *(const float4*)(b + fb + 4);
        float bq[8] = {ba.x, ba.y, ba.z, ba.w, bb.x, bb.y, bb.z, bb.w};
        float inv = 1.f / (S + 1e-16f);
        float h[8];
        #pragma unroll
        for (int j = 0; j < 8; ++j) {
            float v = fmaf(acc[j], inv, bq[j]);
            h[j] = v > 0.f ? v : expm1f(v);
        }
        *(float4*)(out + (size_t)node * D_H + fb)     = make_float4(h[0], h[1], h[2], h[3]);
        *(float4*)(out + (size_t)node * D_H + fb + 4) = make_float4(h[4], h[5], h[6], h[7]);
    }
}

// ---- global mean pool (batch is sorted): register accumulate, flush on change.
// r7 (kept): CHUNK=32 — 4x shorter serial dependent-load chain than 128.
__global__ void pool(const float* __restrict__ h, const int* __restrict__ batch,
                     float* __restrict__ pooled, float* __restrict__ counts) {
    const int CHUNK = 32;
    int base = blockIdx.x * CHUNK;
    int d = threadIdx.x;  // blockDim = 64
    float accv = 0.f; int cur_g = -1; int cnt = 0;
    for (int i = 0; i < CHUNK; ++i) {
        int n = base + i;
        if (n >= N_NODES) break;
        int g = batch[n];
        if (g != cur_g) {
            if (cur_g >= 0) {
                atomicAdd(&pooled[cur_g * D_H + d], accv);
                if (d == 0) atomicAdd(&counts[cur_g], (float)cnt);
            }
            cur_g = g; accv = 0.f; cnt = 0;
        }
        accv += h[(size_t)n * D_H + d];
        cnt++;
    }
    if (cur_g >= 0) {
        atomicAdd(&pooled[cur_g * D_H + d], accv);
        if (d == 0) atomicAdd(&counts[cur_g], (float)cnt);
    }
}

__global__ void classify(const float* __restrict__ pooled, const float* __restrict__ counts,
                         const float* __restrict__ Wc, const float* __restrict__ bc,
                         float* __restrict__ out) {
    int tid = threadIdx.x;             // 640 threads
    int g = tid / N_CLS, c = tid % N_CLS;
    if (g >= N_GRAPHS) return;
    float inv = 1.0f / fmaxf(counts[g], 1.0f);
    float a = bc[c];
    for (int k = 0; k < D_H; ++k)
        a = fmaf(pooled[g * D_H + k] * inv, Wc[k * N_CLS + c], a);
    out[g * N_CLS + c] = a;
}

extern "C" void kernel_launch(void* const* d_in, const int* in_sizes, int n_in,
                              void* d_out, int out_size, void* d_ws, size_t ws_size,
                              hipStream_t stream) {
    const float* x     = (const float*)d_in[0];
    const int*   ei    = (const int*)d_in[1];
    const float* eattr = (const float*)d_in[2];
    const int*   batch = (const int*)d_in[3];
    const float *Wl1 = (const float*)d_in[4],  *bl1 = (const float*)d_in[5];
    const float *Wr1 = (const float*)d_in[6],  *br1 = (const float*)d_in[7];
    const float *We1 = (const float*)d_in[8],  *att1 = (const float*)d_in[9];
    const float *b1  = (const float*)d_in[10];
    const float *Wl2 = (const float*)d_in[11], *bl2 = (const float*)d_in[12];
    const float *Wr2 = (const float*)d_in[13], *br2 = (const float*)d_in[14];
    const float *We2 = (const float*)d_in[15], *att2 = (const float*)d_in[16];
    const float *b2  = (const float*)d_in[17];
    const float *Wc  = (const float*)d_in[18], *bc = (const float*)d_in[19];
    float* out = (float*)d_out;

    const int* src = ei;
    const int* dst = ei + N_EDGES;

    // workspace layout. stg (int2, 15.36 MB) is dead after scatter; xl/xr (fp16,
    // 6.4 MB each) + h (fp32, 12.8 MB) = 25.6 MB alias its region. csr_pack kept
    // at the old 30.72 MB offset so it stays clear of xl/xr/h.
    char* base = (char*)d_ws;
    int2*  stg     = (int2*)base;                       // NB*CAP*8B = 15.36 MB
    __half* xl     = (__half*)base;                     // N*64 fp16 (6.4 MB)
    __half* xr     = xl + (size_t)N_NODES * D_H;        // N*64 fp16
    float* h       = (float*)(xr + (size_t)N_NODES * D_H); // N*64 fp32 (12.8 MB)
    int2*  csr_pack = (int2*)(base + (size_t)NB * CAP * 16); // E2 (8B) = 13.2 MB
    int*   row_start = (int*)(csr_pack + E2);           // N+1
    int*   cnt     = row_start + N_NODES + 1;           // N
    float* esum    = (float*)(cnt + N_NODES);           // 32 lines (32*PAD floats)
    int*   bcursor = (int*)(esum + 32 * PAD);           // NB lines (NB*PAD ints)
    int*   cursor  = bcursor + NB * PAD;                // N
    int*   partial = cursor + N_NODES;                  // NBLK
    float* pooled  = (float*)(partial + NBLK);          // 64*64
    float* counts  = pooled + N_GRAPHS * D_H;           // 64

    int gat_blocks = (N_NODES + 31) / 32;               // 32 nodes per 256-thr block
    int mfma_blocks = (N_NODES + 63) / 64;              // 64 nodes per block

    hipMemsetAsync(cnt, 0, (N_NODES + 32 * PAD + NB * PAD) * sizeof(int), stream);
    hipMemsetAsync(pooled, 0, (N_GRAPHS * D_H + N_GRAPHS) * sizeof(float), stream);

    // ---- CSR build: stage -> LDS hist -> scan -> slice-scatter ----
    bucket_stage<<<(N_EDGES / EPT + 255) / 256, 256, 0, stream>>>(
        src, dst, eattr, esum, bcursor, stg);
    hist_bucket<<<NB * HBB, 256, 0, stream>>>(stg, bcursor, cnt);
    scan_block<<<NBLK, SCAN_BS, 0, stream>>>(cnt, row_start, partial);
    add_offsets<<<NBLK, SCAN_BS, 0, stream>>>(row_start, partial, cursor, esum, csr_pack);
    scatter_slice<<<SLICES * 32, 1024, 0, stream>>>(stg, bcursor, row_start, csr_pack);

    // ---------------- layer 1 ----------------
    linear_dual_mfma<D_IN><<<mfma_blocks, 256, 0, stream>>>(x, Wl1, bl1, Wr1, br1, xl, xr);
    gat_fused<<<gat_blocks, 256, 0, stream>>>(row_start, csr_pack, xl, xr, We1, att1, b1, h);

    // ---------------- layer 2 ----------------
    linear_dual_mfma<D_H><<<mfma_blocks, 256, 0, stream>>>(h, Wl2, bl2, Wr2, br2, xl, xr);
    gat_fused<<<gat_blocks, 256, 0, stream>>>(row_start, csr_pack, xl, xr, We2, att2, b2, h);

    // ---------------- pool + classify ----------------
    pool<<<(N_NODES + 31) / 32, 64, 0, stream>>>(h, batch, pooled, counts);
    classify<<<1, 640, 0, stream>>>(pooled, counts, Wc, bc, out);
}

// Round 16
// 303.903 us; speedup vs baseline: 1.1303x; 1.0131x over previous
//
#include <hip/hip_runtime.h>
#include <hip/hip_fp16.h>
#include <math.h>

#define N_NODES 50000
#define N_EDGES 1600000
#define D_IN 128
#define D_H 64
#define N_CLS 10
#define N_GRAPHS 64
#define NEG_SLOPE 0.2f
#define E2 (N_EDGES + N_NODES)   // edges + self loops
#define SCAN_BS 256
#define NBLK ((N_NODES + SCAN_BS - 1) / SCAN_BS)   // 196 <= 256

// bucketed scatter params
#define NB 25                 // buckets: dst >> 11 (50000/2048 -> 0..24)
#define BSH 11
#define CAP 76800             // per-bucket staging capacity (>40 sigma over E/NB)
#define HBB 8                 // hist blocks per bucket
#define EPT 8                 // edges/thread in bucket_stage
#define PAD 32                // 128B stride: one cache line per contended counter
#define SLICES 8              // node-slices per bucket in scatter_slice
#define SLICE_W (2048 / SLICES)   // 256 nodes per slice

// packed fp16 via clang ext_vector — plain operators lower to v_pk_*_f16.
// (r5 lesson: ROCm 7.2 hip_fp16.h has NO __hmax2/__hmul2 half2 intrinsics.)
typedef _Float16 f16x2 __attribute__((ext_vector_type(2)));
typedef _Float16 f16x4 __attribute__((ext_vector_type(4)));
typedef float    fv4   __attribute__((ext_vector_type(4)));

__device__ inline f16x2 as_h2(unsigned u) { return __builtin_bit_cast(f16x2, u); }
__device__ inline int h2_as_int(f16x2 v) { return __builtin_bit_cast(int, v); }

__device__ inline f16x2 pk_leaky(f16x2 m, f16x2 ns) {
#if __has_builtin(__builtin_elementwise_max)
    return __builtin_elementwise_max(m, m * ns);
#else
    f16x2 p = m * ns, r;
    r.x = m.x > p.x ? m.x : p.x;
    r.y = m.y > p.y ? m.y : p.y;
    return r;
#endif
}

#if __has_builtin(__builtin_amdgcn_fdot2)
__device__ inline float fdot2a(f16x2 a, f16x2 b, float c) {
    return __builtin_amdgcn_fdot2(a, b, c, false);
}
#else
__device__ inline float fdot2a(f16x2 a, f16x2 b, float c) {
    return fmaf((float)a.x, (float)b.x, fmaf((float)a.y, (float)b.y, c));
}
#endif

__device__ inline float wave_reduce_sum(float v) {
    for (int off = 32; off; off >>= 1) v += __shfl_xor(v, off);
    return v;
}

// ===== pass A: bucket-stage edges + eattr sum.
// r0 fix (verified): contended-line atomics were the serializer. esum spread
// over 32 lines, bcursor one line per bucket, EPT=8, int2 staging.
// r4: eattr staged as half2(a,a) so gat's hot loop needs no per-edge cvt.
__global__ void bucket_stage(const int* __restrict__ src, const int* __restrict__ dst,
                             const float* __restrict__ eattr,
                             float* esum, int* bcursor,
                             int2* __restrict__ stg) {
    __shared__ int bcnt[4][32];
    __shared__ int woff[4][32];
    __shared__ float esh[4];
    int t = threadIdx.x;
    int wave = t >> 6;
    if (t < 128) bcnt[t >> 5][t & 31] = 0;
    __syncthreads();
    int e0 = (blockIdx.x * blockDim.x + t) * EPT;   // N_EDGES % EPT == 0
    int ss[EPT], tt[EPT], aa[EPT], r[EPT], b[EPT];
    float v = 0.f;
    bool valid = e0 < N_EDGES;
    if (valid) {
        #pragma unroll
        for (int q = 0; q < EPT / 4; ++q) {
            int4 s4 = *(const int4*)(src + e0 + 4 * q);
            int4 t4 = *(const int4*)(dst + e0 + 4 * q);
            float4 a4 = *(const float4*)(eattr + e0 + 4 * q);
            ss[4*q] = s4.x; ss[4*q+1] = s4.y; ss[4*q+2] = s4.z; ss[4*q+3] = s4.w;
            tt[4*q] = t4.x; tt[4*q+1] = t4.y; tt[4*q+2] = t4.z; tt[4*q+3] = t4.w;
            aa[4*q]   = h2_as_int((f16x2){(_Float16)a4.x, (_Float16)a4.x});
            aa[4*q+1] = h2_as_int((f16x2){(_Float16)a4.y, (_Float16)a4.y});
            aa[4*q+2] = h2_as_int((f16x2){(_Float16)a4.z, (_Float16)a4.z});
            aa[4*q+3] = h2_as_int((f16x2){(_Float16)a4.w, (_Float16)a4.w});
            v += (a4.x + a4.y) + (a4.z + a4.w);
        }
        #pragma unroll
        for (int i = 0; i < EPT; ++i) {
            b[i] = tt[i] >> BSH;
            r[i] = atomicAdd(&bcnt[wave][b[i]], 1);
        }
    }
    v = wave_reduce_sum(v);
    if ((t & 63) == 0) esh[wave] = v;
    __syncthreads();
    if (t < NB) {
        int c0 = bcnt[0][t], c1 = bcnt[1][t], c2 = bcnt[2][t], c3 = bcnt[3][t];
        int tot = c0 + c1 + c2 + c3;
        int base = tot ? atomicAdd(&bcursor[t * PAD], tot) : 0;
        woff[0][t] = base;
        woff[1][t] = base + c0;
        woff[2][t] = base + c0 + c1;
        woff[3][t] = base + c0 + c1 + c2;
    }
    if (t == 0) {
        float tot = (esh[0] + esh[1]) + (esh[2] + esh[3]);
        atomicAdd(&esum[(blockIdx.x & 31) * PAD], tot);   // 32 distinct lines
    }
    __syncthreads();
    if (valid) {
        #pragma unroll
        for (int i = 0; i < EPT; ++i) {
            int p = b[i] * CAP + woff[wave][b[i]] + r[i];
            stg[p] = make_int2((ss[i] & 0xFFFF) | ((tt[i] & 2047) << 16), aa[i]);
        }
    }
}

// ===== pass A2: per-node histogram from staged dst-low bits, LDS-resident window
__global__ void hist_bucket(const int2* __restrict__ stg, const int* __restrict__ bcursor,
                            int* cnt) {
    __shared__ int hist[2048];
    int b = blockIdx.x / HBB;
    int j = blockIdx.x % HBB;
    for (int i = threadIdx.x; i < 2048; i += 256) hist[i] = 0;
    __syncthreads();
    int n = bcursor[b * PAD];
    const int2* sd = stg + (size_t)b * CAP;
    int per = (n + HBB - 1) / HBB;
    int start = j * per;
    int end = min(start + per, n);
    for (int idx = start + threadIdx.x; idx < end; idx += 256)
        atomicAdd(&hist[(sd[idx].x >> 16) & 2047], 1);
    __syncthreads();
    int nb = b << BSH;
    for (int i = threadIdx.x; i < 2048; i += 256) {
        int c = hist[i];
        if (c) atomicAdd(&cnt[nb + i], c);
    }
}

// ---- block-local exclusive scan; +1 per node folds in the self-loop slot ----
__global__ void scan_block(const int* __restrict__ cnt, int* __restrict__ row_start,
                           int* __restrict__ partial) {
    __shared__ int sd[SCAN_BS];
    int i = blockIdx.x * SCAN_BS + threadIdx.x;
    int v = (i < N_NODES) ? (cnt[i] + 1) : 0;   // +1 = self loop
    sd[threadIdx.x] = v;
    __syncthreads();
    for (int off = 1; off < SCAN_BS; off <<= 1) {
        int t = (threadIdx.x >= off) ? sd[threadIdx.x - off] : 0;
        __syncthreads();
        sd[threadIdx.x] += t;
        __syncthreads();
    }
    if (i < N_NODES) row_start[i] = sd[threadIdx.x] - v;
    if (threadIdx.x == SCAN_BS - 1) partial[blockIdx.x] = sd[threadIdx.x];
}
// finalize row_start (redundant LDS scan of partials replaces a launch),
// write self-loop CSR entry (eattr-mean as half2), seed cursor
__global__ void add_offsets(int* __restrict__ row_start, const int* __restrict__ partial,
                            int* __restrict__ cursor, const float* __restrict__ esum,
                            int2* __restrict__ csr_pack) {
    __shared__ int sp[SCAN_BS];
    int pv = (threadIdx.x < NBLK) ? partial[threadIdx.x] : 0;
    sp[threadIdx.x] = pv;
    __syncthreads();
    for (int off = 1; off < SCAN_BS; off <<= 1) {
        int t = (threadIdx.x >= off) ? sp[threadIdx.x - off] : 0;
        __syncthreads();
        sp[threadIdx.x] += t;
        __syncthreads();
    }
    float es = 0.f;
    #pragma unroll
    for (int jj = 0; jj < 32; ++jj) es += esum[jj * PAD];
    float esm = es * (1.0f / N_EDGES);
    int ebits = h2_as_int((f16x2){(_Float16)esm, (_Float16)esm});
    int base = (blockIdx.x == 0) ? 0 : sp[blockIdx.x - 1];
    int i = blockIdx.x * SCAN_BS + threadIdx.x;
    if (i < N_NODES) {
        int r = row_start[i] + base;
        row_start[i] = r;
        csr_pack[r] = make_int2(i, ebits);
        cursor[i] = r + 1;
    }
    if (i == 0) row_start[N_NODES] = E2;
}

// ===== pass B (r3-verified): slice-owned scatter, LDS cursors, deep MLP.
__global__ __launch_bounds__(1024) void scatter_slice(
                              const int2* __restrict__ stg,
                              const int* __restrict__ bcursor,
                              const int* __restrict__ row_start,
                              int2* __restrict__ csr_pack) {
    __shared__ int lcur[SLICE_W];
    int b = blockIdx.x & 31;
    int m = blockIdx.x >> 5;
    if (b >= NB) return;
    int nbase = (b << BSH) + m * SLICE_W;
    for (int i = threadIdx.x; i < SLICE_W; i += 1024) {
        int node = nbase + i;
        lcur[i] = (node < N_NODES) ? row_start[node] + 1 : 0;  // +1 skips self-loop slot
    }
    __syncthreads();
    int n = bcursor[b * PAD];
    const int4* sd4 = (const int4*)(stg + (size_t)b * CAP);   // b*CAP*8B is 16B-aligned
    int n4 = n >> 1;
    int lo = m * SLICE_W, hi = lo + SLICE_W;
    for (int base4 = 0; base4 < n4; base4 += 4096) {
        int4 e[4];
        int idx[4];
        #pragma unroll
        for (int j = 0; j < 4; ++j) {
            idx[j] = base4 + j * 1024 + (int)threadIdx.x;
            if (idx[j] < n4) e[j] = sd4[idx[j]];
        }
        #pragma unroll
        for (int j = 0; j < 4; ++j) {
            if (idx[j] < n4) {
                int dl0 = (e[j].x >> 16) & 2047;
                if (dl0 >= lo && dl0 < hi) {
                    int q = atomicAdd(&lcur[dl0 - lo], 1);
                    csr_pack[q] = make_int2(e[j].x & 0xFFFF, e[j].y);
                }
                int dl1 = (e[j].z >> 16) & 2047;
                if (dl1 >= lo && dl1 < hi) {
                    int q = atomicAdd(&lcur[dl1 - lo], 1);
                    csr_pack[q] = make_int2(e[j].z & 0xFFFF, e[j].w);
                }
            }
        }
    }
    if ((n & 1) && threadIdx.x == 0) {   // odd tail edge; only owning slice stores
        int2 e = stg[(size_t)b * CAP + n - 1];
        int dl = (e.x >> 16) & 2047;
        if (dl >= lo && dl < hi) {
            int q = atomicAdd(&lcur[dl - lo], 1);
            csr_pack[q] = make_int2(e.x & 0xFFFF, e.y);
        }
    }
}

// ---- r14-verified: MFMA dual-linear (v_mfma_f32_16x16x16_f16, swapped
// operands, fp32 accumulate; absmax unchanged at 4.88e-4). 43.8 -> <~15us.
template<int K>
__global__ __launch_bounds__(256) void linear_dual_mfma(
        const float* __restrict__ x,
        const float* __restrict__ Wl, const float* __restrict__ bl,
        const float* __restrict__ Wr, const float* __restrict__ br,
        __half* __restrict__ xl, __half* __restrict__ xr) {
    const int KS = K + 4;                    // padded LDS stride (f16 units)
    __shared__ _Float16 Xh[64 * KS];         // 64 nodes x K
    __shared__ _Float16 Wt[128 * KS];        // Wt[c][k]; c<64: Wl, c>=64: Wr
    int t = threadIdx.x;
    int nb = blockIdx.x * 64;
    // stage X (fp32 -> fp16), zero-fill invalid rows
    for (int i = t; i < 64 * (K / 4); i += 256) {
        int n = i / (K / 4), k0 = (i % (K / 4)) * 4;
        float4 v = (nb + n < N_NODES) ? *(const float4*)(x + (size_t)(nb + n) * K + k0)
                                      : make_float4(0.f, 0.f, 0.f, 0.f);
        f16x4 h = {(_Float16)v.x, (_Float16)v.y, (_Float16)v.z, (_Float16)v.w};
        *(f16x4*)&Xh[n * KS + k0] = h;
    }
    // stage W transposed (coalesced reads, scattered u16 LDS writes)
    for (int i = t; i < K * 64; i += 256) {
        int k = i >> 6, c = i & 63;
        Wt[c * KS + k] = (_Float16)Wl[i];
    }
    for (int i = t; i < K * 64; i += 256) {
        int k = i >> 6, c = i & 63;
        Wt[(c + 64) * KS + k] = (_Float16)Wr[i];
    }
    __syncthreads();

    int w = t >> 6, lane = t & 63;
    int np = lane & 15;                      // node within wave tile (B col / D col)
    int g  = lane >> 4;                      // quad index
    int node = nb + w * 16 + np;
    const _Float16* xrow = &Xh[(w * 16 + np) * KS];
    fv4 acc0 = {0.f,0.f,0.f,0.f}, acc1 = {0.f,0.f,0.f,0.f};
    fv4 acc2 = {0.f,0.f,0.f,0.f}, acc3 = {0.f,0.f,0.f,0.f};
    fv4 acc4 = {0.f,0.f,0.f,0.f}, acc5 = {0.f,0.f,0.f,0.f};
    fv4 acc6 = {0.f,0.f,0.f,0.f}, acc7 = {0.f,0.f,0.f,0.f};

#if __has_builtin(__builtin_amdgcn_mfma_f32_16x16x16f16)
    for (int k0 = 0; k0 < K; k0 += 16) {
        f16x4 bf = *(const f16x4*)&xrow[k0 + 4 * g];                 // B = X^T frag
        f16x4 a0 = *(const f16x4*)&Wt[(0 * 16 + np) * KS + k0 + 4 * g];
        f16x4 a1 = *(const f16x4*)&Wt[(1 * 16 + np) * KS + k0 + 4 * g];
        f16x4 a2 = *(const f16x4*)&Wt[(2 * 16 + np) * KS + k0 + 4 * g];
        f16x4 a3 = *(const f16x4*)&Wt[(3 * 16 + np) * KS + k0 + 4 * g];
        f16x4 a4 = *(const f16x4*)&Wt[(4 * 16 + np) * KS + k0 + 4 * g];
        f16x4 a5 = *(const f16x4*)&Wt[(5 * 16 + np) * KS + k0 + 4 * g];
        f16x4 a6 = *(const f16x4*)&Wt[(6 * 16 + np) * KS + k0 + 4 * g];
        f16x4 a7 = *(const f16x4*)&Wt[(7 * 16 + np) * KS + k0 + 4 * g];
        acc0 = __builtin_amdgcn_mfma_f32_16x16x16f16(a0, bf, acc0, 0, 0, 0);
        acc1 = __builtin_amdgcn_mfma_f32_16x16x16f16(a1, bf, acc1, 0, 0, 0);
        acc2 = __builtin_amdgcn_mfma_f32_16x16x16f16(a2, bf, acc2, 0, 0, 0);
        acc3 = __builtin_amdgcn_mfma_f32_16x16x16f16(a3, bf, acc3, 0, 0, 0);
        acc4 = __builtin_amdgcn_mfma_f32_16x16x16f16(a4, bf, acc4, 0, 0, 0);
        acc5 = __builtin_amdgcn_mfma_f32_16x16x16f16(a5, bf, acc5, 0, 0, 0);
        acc6 = __builtin_amdgcn_mfma_f32_16x16x16f16(a6, bf, acc6, 0, 0, 0);
        acc7 = __builtin_amdgcn_mfma_f32_16x16x16f16(a7, bf, acc7, 0, 0, 0);
    }
#else
    // scalar fallback, bit-equivalent lane->element mapping (slow, correct)
    {
        fv4* accs[8] = {&acc0,&acc1,&acc2,&acc3,&acc4,&acc5,&acc6,&acc7};
        for (int ct = 0; ct < 8; ++ct)
            for (int j = 0; j < 4; ++j) {
                float s = 0.f;
                const _Float16* wrow = &Wt[(ct * 16 + 4 * g + j) * KS];
                for (int k = 0; k < K; ++k) s += (float)wrow[k] * (float)xrow[k];
                (*accs[ct])[j] = s;
            }
    }
#endif

    // epilogue: lane holds c = 16*ct + 4*g + j for node `node`
    if (node < N_NODES) {
        #define EMIT(CT, ACC)                                                        \
        {                                                                            \
            const float* bp = ((CT) < 4) ? (bl + (CT) * 16 + 4 * g)                  \
                                         : (br + ((CT) - 4) * 16 + 4 * g);           \
            float4 bv = *(const float4*)bp;                                          \
            f16x4 o = {(_Float16)(ACC[0] + bv.x), (_Float16)(ACC[1] + bv.y),         \
                       (_Float16)(ACC[2] + bv.z), (_Float16)(ACC[3] + bv.w)};        \
            __half* dst = ((CT) < 4)                                                 \
                ? (xl + (size_t)node * D_H + (CT) * 16 + 4 * g)                      \
                : (xr + (size_t)node * D_H + ((CT) - 4) * 16 + 4 * g);               \
            *(f16x4*)dst = o;                                                        \
        }
        EMIT(0, acc0) EMIT(1, acc1) EMIT(2, acc2) EMIT(3, acc3)
        EMIT(4, acc4) EMIT(5, acc5) EMIT(6, acc6) EMIT(7, acc7)
        #undef EMIT
    }
}

// ---- fused GATv2 layer — r9-verified 8-lane-group design. r15: FUSE=1
// (layer 2) folds global-mean-pool into the epilogue: batch is SORTED, so a
// 32-node block spans <=2 graphs (sizes ~781+-28; 4 LDS slots for margin).
// LDS fp32-atomic accumulate -> 256-thread flush (4 slots x 64 dims), ~200K
// well-spread global atomics (49/addr, r0 calibration ~0.8us). Deletes the
// 12.8MB h-write + 12.8MB h-read + pool dispatch. FUSE=0 (layer 1) writes
// `out` as before (feeds lin2).
template<int FUSE>
__global__ __launch_bounds__(256) void gat_fused(
        const int* __restrict__ row_start, const int2* __restrict__ csr_pack,
        const __half* __restrict__ xl, const __half* __restrict__ xr,
        const float* __restrict__ We, const float* __restrict__ att,
        const float* __restrict__ b, float* __restrict__ out,
        const int* __restrict__ batch, float* __restrict__ pooled,
        float* __restrict__ counts) {
    __shared__ float pl[4][D_H];
    __shared__ int pcnt[4];
    __shared__ int gbase_s;
    if (FUSE) {
        int tt = threadIdx.x;
        if (tt < 4 * D_H) pl[tt >> 6][tt & 63] = 0.f;
        if (tt < 4) pcnt[tt] = 0;
        if (tt == 0) gbase_s = batch[blockIdx.x * 32];   // first node of block
        __syncthreads();
    }
    int lane = threadIdx.x & 63;
    int g = lane >> 3;                      // 8 groups per wave
    int s = lane & 7;                       // 8 lanes per group
    int wid = blockIdx.x * (blockDim.x >> 6) + (threadIdx.x >> 6);
    int node = wid * 8 + g;                 // 32 nodes per 256-thread block
    bool nv = node < N_NODES;
    int nodec = nv ? node : 0;
    int fb = s * 8;                         // 8 dims per lane
    float4 wea = *(const float4*)(We + fb), web = *(const float4*)(We + fb + 4);
    float4 ata = *(const float4*)(att + fb), atb = *(const float4*)(att + fb + 4);
    f16x2 we[4] = {{(_Float16)wea.x, (_Float16)wea.y}, {(_Float16)wea.z, (_Float16)wea.w},
                   {(_Float16)web.x, (_Float16)web.y}, {(_Float16)web.z, (_Float16)web.w}};
    f16x2 at[4] = {{(_Float16)ata.x, (_Float16)ata.y}, {(_Float16)ata.z, (_Float16)ata.w},
                   {(_Float16)atb.x, (_Float16)atb.y}, {(_Float16)atb.z, (_Float16)atb.w}};
    int4 xru = *(const int4*)(xr + (size_t)nodec * D_H + fb);   // 16B, aligned
    f16x2 xr4[4] = {as_h2((unsigned)xru.x), as_h2((unsigned)xru.y),
                    as_h2((unsigned)xru.z), as_h2((unsigned)xru.w)};
    const f16x2 ns = {(_Float16)NEG_SLOPE, (_Float16)NEG_SLOPE};
    int j0 = 0, j1 = 0;
    if (nv) { j0 = row_start[node]; j1 = row_start[node + 1]; }

    float S = 0.f;
    float acc[8] = {0.f, 0.f, 0.f, 0.f, 0.f, 0.f, 0.f, 0.f};

    for (int i0 = j0; i0 < j1; i0 += 4) {   // same trip count across each 8-lane group
        int2 pk[4]; int4 qk[4]; bool vk[4];
        #pragma unroll
        for (int k = 0; k < 4; ++k) {
            vk[k] = (i0 + k) < j1;
            int c = vk[k] ? (i0 + k) : i0;
            pk[k] = csr_pack[c];
        }
        #pragma unroll
        for (int k = 0; k < 4; ++k)
            qk[k] = *(const int4*)(xl + (size_t)pk[k].x * D_H + fb);   // 16B gather
        float t[4];
        #pragma unroll
        for (int k = 0; k < 4; ++k) {
            f16x2 a2 = as_h2((unsigned)pk[k].y);
            f16x2 r0 = as_h2((unsigned)qk[k].x), r1 = as_h2((unsigned)qk[k].y);
            f16x2 r2 = as_h2((unsigned)qk[k].z), r3 = as_h2((unsigned)qk[k].w);
            f16x2 m0 = a2 * we[0] + (r0 + xr4[0]);
            f16x2 m1 = a2 * we[1] + (r1 + xr4[1]);
            f16x2 m2 = a2 * we[2] + (r2 + xr4[2]);
            f16x2 m3 = a2 * we[3] + (r3 + xr4[3]);
            m0 = pk_leaky(m0, ns); m1 = pk_leaky(m1, ns);
            m2 = pk_leaky(m2, ns); m3 = pk_leaky(m3, ns);
            t[k] = fdot2a(m3, at[3], fdot2a(m2, at[2],
                   fdot2a(m1, at[1], fdot2a(m0, at[0], 0.f))));
        }
        #pragma unroll
        for (int off = 1; off <= 4; off <<= 1) {   // reduce within 8-lane group
            t[0] += __shfl_xor(t[0], off);
            t[1] += __shfl_xor(t[1], off);
            t[2] += __shfl_xor(t[2], off);
            t[3] += __shfl_xor(t[3], off);
        }
        #pragma unroll
        for (int k = 0; k < 4; ++k) {
            float z = vk[k] ? __expf(t[k]) : 0.f;
            S += z;
            f16x2 r0 = as_h2((unsigned)qk[k].x), r1 = as_h2((unsigned)qk[k].y);
            f16x2 r2 = as_h2((unsigned)qk[k].z), r3 = as_h2((unsigned)qk[k].w);
            acc[0] = fmaf(z, (float)r0.x, acc[0]);
            acc[1] = fmaf(z, (float)r0.y, acc[1]);
            acc[2] = fmaf(z, (float)r1.x, acc[2]);
            acc[3] = fmaf(z, (float)r1.y, acc[3]);
            acc[4] = fmaf(z, (float)r2.x, acc[4]);
            acc[5] = fmaf(z, (float)r2.y, acc[5]);
            acc[6] = fmaf(z, (float)r3.x, acc[6]);
            acc[7] = fmaf(z, (float)r3.y, acc[7]);
        }
    }

    if (nv) {
        float4 ba = *(const float4*)(b + fb), bb = *(const float4*)(b + fb + 4);
        float bq[8] = {ba.x, ba.y, ba.z, ba.w, bb.x, bb.y, bb.z, bb.w};
        float inv = 1.f / (S + 1e-16f);
        float h[8];
        #pragma unroll
        for (int j = 0; j < 8; ++j) {
            float v = fmaf(acc[j], inv, bq[j]);
            h[j] = v > 0.f ? v : expm1f(v);
        }
        if (FUSE) {
            int gi = batch[node] - gbase_s;
            gi = gi < 0 ? 0 : (gi > 3 ? 3 : gi);   // sorted batch: realistically <=1
            #pragma unroll
            for (int j = 0; j < 8; ++j) atomicAdd(&pl[gi][fb + j], h[j]);
            if (s == 0) atomicAdd(&pcnt[gi], 1);   // one count per node
        } else {
            *(float4*)(out + (size_t)node * D_H + fb)     = make_float4(h[0], h[1], h[2], h[3]);
            *(float4*)(out + (size_t)node * D_H + fb + 4) = make_float4(h[4], h[5], h[6], h[7]);
        }
    }
    if (FUSE) {
        __syncthreads();
        int tt = threadIdx.x;                 // 256 threads = 4 slots x 64 dims
        int gi = tt >> 6, d = tt & 63;
        int c = pcnt[gi];
        if (c > 0) {
            int gg = gbase_s + gi;
            atomicAdd(&pooled[gg * D_H + d], pl[gi][d]);
            if (d == 0) atomicAdd(&counts[gg], (float)c);
        }
    }
}

__global__ void classify(const float* __restrict__ pooled, const float* __restrict__ counts,
                         const float* __restrict__ Wc, const float* __restrict__ bc,
                         float* __restrict__ out) {
    int tid = threadIdx.x;             // 640 threads
    int g = tid / N_CLS, c = tid % N_CLS;
    if (g >= N_GRAPHS) return;
    float inv = 1.0f / fmaxf(counts[g], 1.0f);
    float a = bc[c];
    for (int k = 0; k < D_H; ++k)
        a = fmaf(pooled[g * D_H + k] * inv, Wc[k * N_CLS + c], a);
    out[g * N_CLS + c] = a;
}

extern "C" void kernel_launch(void* const* d_in, const int* in_sizes, int n_in,
                              void* d_out, int out_size, void* d_ws, size_t ws_size,
                              hipStream_t stream) {
    const float* x     = (const float*)d_in[0];
    const int*   ei    = (const int*)d_in[1];
    const float* eattr = (const float*)d_in[2];
    const int*   batch = (const int*)d_in[3];
    const float *Wl1 = (const float*)d_in[4],  *bl1 = (const float*)d_in[5];
    const float *Wr1 = (const float*)d_in[6],  *br1 = (const float*)d_in[7];
    const float *We1 = (const float*)d_in[8],  *att1 = (const float*)d_in[9];
    const float *b1  = (const float*)d_in[10];
    const float *Wl2 = (const float*)d_in[11], *bl2 = (const float*)d_in[12];
    const float *Wr2 = (const float*)d_in[13], *br2 = (const float*)d_in[14];
    const float *We2 = (const float*)d_in[15], *att2 = (const float*)d_in[16];
    const float *b2  = (const float*)d_in[17];
    const float *Wc  = (const float*)d_in[18], *bc = (const float*)d_in[19];
    float* out = (float*)d_out;

    const int* src = ei;
    const int* dst = ei + N_EDGES;

    // workspace layout. stg (int2, 15.36 MB) is dead after scatter; xl/xr (fp16,
    // 6.4 MB each) + h (fp32, 12.8 MB) = 25.6 MB alias its region. csr_pack kept
    // at the old 30.72 MB offset so it stays clear of xl/xr/h.
    char* base = (char*)d_ws;
    int2*  stg     = (int2*)base;                       // NB*CAP*8B = 15.36 MB
    __half* xl     = (__half*)base;                     // N*64 fp16 (6.4 MB)
    __half* xr     = xl + (size_t)N_NODES * D_H;        // N*64 fp16
    float* h       = (float*)(xr + (size_t)N_NODES * D_H); // N*64 fp32 (12.8 MB)
    int2*  csr_pack = (int2*)(base + (size_t)NB * CAP * 16); // E2 (8B) = 13.2 MB
    int*   row_start = (int*)(csr_pack + E2);           // N+1
    int*   cnt     = row_start + N_NODES + 1;           // N
    float* esum    = (float*)(cnt + N_NODES);           // 32 lines (32*PAD floats)
    int*   bcursor = (int*)(esum + 32 * PAD);           // NB lines (NB*PAD ints)
    int*   cursor  = bcursor + NB * PAD;                // N
    int*   partial = cursor + N_NODES;                  // NBLK
    float* pooled  = (float*)(partial + NBLK);          // 64*64
    float* counts  = pooled + N_GRAPHS * D_H;           // 64

    int gat_blocks = (N_NODES + 31) / 32;               // 32 nodes per 256-thr block
    int mfma_blocks = (N_NODES + 63) / 64;              // 64 nodes per block

    hipMemsetAsync(cnt, 0, (N_NODES + 32 * PAD + NB * PAD) * sizeof(int), stream);
    hipMemsetAsync(pooled, 0, (N_GRAPHS * D_H + N_GRAPHS) * sizeof(float), stream);

    // ---- CSR build: stage -> LDS hist -> scan -> slice-scatter ----
    bucket_stage<<<(N_EDGES / EPT + 255) / 256, 256, 0, stream>>>(
        src, dst, eattr, esum, bcursor, stg);
    hist_bucket<<<NB * HBB, 256, 0, stream>>>(stg, bcursor, cnt);
    scan_block<<<NBLK, SCAN_BS, 0, stream>>>(cnt, row_start, partial);
    add_offsets<<<NBLK, SCAN_BS, 0, stream>>>(row_start, partial, cursor, esum, csr_pack);
    scatter_slice<<<SLICES * 32, 1024, 0, stream>>>(stg, bcursor, row_start, csr_pack);

    // ---------------- layer 1 ----------------
    linear_dual_mfma<D_IN><<<mfma_blocks, 256, 0, stream>>>(x, Wl1, bl1, Wr1, br1, xl, xr);
    gat_fused<0><<<gat_blocks, 256, 0, stream>>>(row_start, csr_pack, xl, xr,
                                                 We1, att1, b1, h, batch, pooled, counts);

    // ---------------- layer 2 ----------------
    linear_dual_mfma<D_H><<<mfma_blocks, 256, 0, stream>>>(h, Wl2, bl2, Wr2, br2, xl, xr);
    gat_fused<1><<<gat_blocks, 256, 0, stream>>>(row_start, csr_pack, xl, xr,
                                                 We2, att2, b2, h, batch, pooled, counts);

    // ---------------- pool folded into gat layer 2; classify only ----------------
    classify<<<1, 640, 0, stream>>>(pooled, counts, Wc, bc, out);
}

// Round 17
// 294.882 us; speedup vs baseline: 1.1648x; 1.0306x over previous
//
#include <hip/hip_runtime.h>
#include <hip/hip_fp16.h>
#include <math.h>

#define N_NODES 50000
#define N_EDGES 1600000
#define D_IN 128
#define D_H 64
#define N_CLS 10
#define N_GRAPHS 64
#define NEG_SLOPE 0.2f
#define E2 (N_EDGES + N_NODES)   // edges + self loops
#define SCAN_BS 256
#define NBLK ((N_NODES + SCAN_BS - 1) / SCAN_BS)   // 196 <= 256

// bucketed scatter params
#define NB 25                 // buckets: dst >> 11 (50000/2048 -> 0..24)
#define BSH 11
#define CAP 76800             // per-bucket staging capacity (>40 sigma over E/NB)
#define HBB 8                 // hist blocks per bucket
#define EPT 8                 // edges/thread in bucket_stage
#define PAD 32                // 128B stride: one cache line per contended counter
#define SLICES 8              // node-slices per bucket in scatter_slice
#define SLICE_W (2048 / SLICES)   // 256 nodes per slice

// packed fp16 via clang ext_vector — plain operators lower to v_pk_*_f16.
// (r5 lesson: ROCm 7.2 hip_fp16.h has NO __hmax2/__hmul2 half2 intrinsics.)
typedef _Float16 f16x2 __attribute__((ext_vector_type(2)));
typedef _Float16 f16x4 __attribute__((ext_vector_type(4)));
typedef float    fv4   __attribute__((ext_vector_type(4)));

__device__ inline f16x2 as_h2(unsigned u) { return __builtin_bit_cast(f16x2, u); }
__device__ inline int h2_as_int(f16x2 v) { return __builtin_bit_cast(int, v); }

__device__ inline f16x2 pk_leaky(f16x2 m, f16x2 ns) {
#if __has_builtin(__builtin_elementwise_max)
    return __builtin_elementwise_max(m, m * ns);
#else
    f16x2 p = m * ns, r;
    r.x = m.x > p.x ? m.x : p.x;
    r.y = m.y > p.y ? m.y : p.y;
    return r;
#endif
}

#if __has_builtin(__builtin_amdgcn_fdot2)
__device__ inline float fdot2a(f16x2 a, f16x2 b, float c) {
    return __builtin_amdgcn_fdot2(a, b, c, false);
}
#else
__device__ inline float fdot2a(f16x2 a, f16x2 b, float c) {
    return fmaf((float)a.x, (float)b.x, fmaf((float)a.y, (float)b.y, c));
}
#endif

__device__ inline float wave_reduce_sum(float v) {
    for (int off = 32; off; off >>= 1) v += __shfl_xor(v, off);
    return v;
}

// ===== pass A: bucket-stage edges + eattr sum.
// r0 fix (verified): contended-line atomics were the serializer. esum spread
// over 32 lines, bcursor one line per bucket, EPT=8, int2 staging.
// r4: eattr staged as half2(a,a) so gat's hot loop needs no per-edge cvt.
__global__ void bucket_stage(const int* __restrict__ src, const int* __restrict__ dst,
                             const float* __restrict__ eattr,
                             float* esum, int* bcursor,
                             int2* __restrict__ stg) {
    __shared__ int bcnt[4][32];
    __shared__ int woff[4][32];
    __shared__ float esh[4];
    int t = threadIdx.x;
    int wave = t >> 6;
    if (t < 128) bcnt[t >> 5][t & 31] = 0;
    __syncthreads();
    int e0 = (blockIdx.x * blockDim.x + t) * EPT;   // N_EDGES % EPT == 0
    int ss[EPT], tt[EPT], aa[EPT], r[EPT], b[EPT];
    float v = 0.f;
    bool valid = e0 < N_EDGES;
    if (valid) {
        #pragma unroll
        for (int q = 0; q < EPT / 4; ++q) {
            int4 s4 = *(const int4*)(src + e0 + 4 * q);
            int4 t4 = *(const int4*)(dst + e0 + 4 * q);
            float4 a4 = *(const float4*)(eattr + e0 + 4 * q);
            ss[4*q] = s4.x; ss[4*q+1] = s4.y; ss[4*q+2] = s4.z; ss[4*q+3] = s4.w;
            tt[4*q] = t4.x; tt[4*q+1] = t4.y; tt[4*q+2] = t4.z; tt[4*q+3] = t4.w;
            aa[4*q]   = h2_as_int((f16x2){(_Float16)a4.x, (_Float16)a4.x});
            aa[4*q+1] = h2_as_int((f16x2){(_Float16)a4.y, (_Float16)a4.y});
            aa[4*q+2] = h2_as_int((f16x2){(_Float16)a4.z, (_Float16)a4.z});
            aa[4*q+3] = h2_as_int((f16x2){(_Float16)a4.w, (_Float16)a4.w});
            v += (a4.x + a4.y) + (a4.z + a4.w);
        }
        #pragma unroll
        for (int i = 0; i < EPT; ++i) {
            b[i] = tt[i] >> BSH;
            r[i] = atomicAdd(&bcnt[wave][b[i]], 1);
        }
    }
    v = wave_reduce_sum(v);
    if ((t & 63) == 0) esh[wave] = v;
    __syncthreads();
    if (t < NB) {
        int c0 = bcnt[0][t], c1 = bcnt[1][t], c2 = bcnt[2][t], c3 = bcnt[3][t];
        int tot = c0 + c1 + c2 + c3;
        int base = tot ? atomicAdd(&bcursor[t * PAD], tot) : 0;
        woff[0][t] = base;
        woff[1][t] = base + c0;
        woff[2][t] = base + c0 + c1;
        woff[3][t] = base + c0 + c1 + c2;
    }
    if (t == 0) {
        float tot = (esh[0] + esh[1]) + (esh[2] + esh[3]);
        atomicAdd(&esum[(blockIdx.x & 31) * PAD], tot);   // 32 distinct lines
    }
    __syncthreads();
    if (valid) {
        #pragma unroll
        for (int i = 0; i < EPT; ++i) {
            int p = b[i] * CAP + woff[wave][b[i]] + r[i];
            stg[p] = make_int2((ss[i] & 0xFFFF) | ((tt[i] & 2047) << 16), aa[i]);
        }
    }
}

// ===== pass A2: per-node histogram from staged dst-low bits, LDS-resident window
__global__ void hist_bucket(const int2* __restrict__ stg, const int* __restrict__ bcursor,
                            int* cnt) {
    __shared__ int hist[2048];
    int b = blockIdx.x / HBB;
    int j = blockIdx.x % HBB;
    for (int i = threadIdx.x; i < 2048; i += 256) hist[i] = 0;
    __syncthreads();
    int n = bcursor[b * PAD];
    const int2* sd = stg + (size_t)b * CAP;
    int per = (n + HBB - 1) / HBB;
    int start = j * per;
    int end = min(start + per, n);
    for (int idx = start + threadIdx.x; idx < end; idx += 256)
        atomicAdd(&hist[(sd[idx].x >> 16) & 2047], 1);
    __syncthreads();
    int nb = b << BSH;
    for (int i = threadIdx.x; i < 2048; i += 256) {
        int c = hist[i];
        if (c) atomicAdd(&cnt[nb + i], c);
    }
}

// ---- block-local exclusive scan; +1 per node folds in the self-loop slot ----
__global__ void scan_block(const int* __restrict__ cnt, int* __restrict__ row_start,
                           int* __restrict__ partial) {
    __shared__ int sd[SCAN_BS];
    int i = blockIdx.x * SCAN_BS + threadIdx.x;
    int v = (i < N_NODES) ? (cnt[i] + 1) : 0;   // +1 = self loop
    sd[threadIdx.x] = v;
    __syncthreads();
    for (int off = 1; off < SCAN_BS; off <<= 1) {
        int t = (threadIdx.x >= off) ? sd[threadIdx.x - off] : 0;
        __syncthreads();
        sd[threadIdx.x] += t;
        __syncthreads();
    }
    if (i < N_NODES) row_start[i] = sd[threadIdx.x] - v;
    if (threadIdx.x == SCAN_BS - 1) partial[blockIdx.x] = sd[threadIdx.x];
}
// finalize row_start (redundant LDS scan of partials replaces a launch),
// write self-loop CSR entry (eattr-mean as half2), seed cursor
__global__ void add_offsets(int* __restrict__ row_start, const int* __restrict__ partial,
                            int* __restrict__ cursor, const float* __restrict__ esum,
                            int2* __restrict__ csr_pack) {
    __shared__ int sp[SCAN_BS];
    int pv = (threadIdx.x < NBLK) ? partial[threadIdx.x] : 0;
    sp[threadIdx.x] = pv;
    __syncthreads();
    for (int off = 1; off < SCAN_BS; off <<= 1) {
        int t = (threadIdx.x >= off) ? sp[threadIdx.x - off] : 0;
        __syncthreads();
        sp[threadIdx.x] += t;
        __syncthreads();
    }
    float es = 0.f;
    #pragma unroll
    for (int jj = 0; jj < 32; ++jj) es += esum[jj * PAD];
    float esm = es * (1.0f / N_EDGES);
    int ebits = h2_as_int((f16x2){(_Float16)esm, (_Float16)esm});
    int base = (blockIdx.x == 0) ? 0 : sp[blockIdx.x - 1];
    int i = blockIdx.x * SCAN_BS + threadIdx.x;
    if (i < N_NODES) {
        int r = row_start[i] + base;
        row_start[i] = r;
        csr_pack[r] = make_int2(i, ebits);
        cursor[i] = r + 1;
    }
    if (i == 0) row_start[N_NODES] = E2;
}

// ===== pass B (r3-verified): slice-owned scatter, LDS cursors, deep MLP.
__global__ __launch_bounds__(1024) void scatter_slice(
                              const int2* __restrict__ stg,
                              const int* __restrict__ bcursor,
                              const int* __restrict__ row_start,
                              int2* __restrict__ csr_pack) {
    __shared__ int lcur[SLICE_W];
    int b = blockIdx.x & 31;
    int m = blockIdx.x >> 5;
    if (b >= NB) return;
    int nbase = (b << BSH) + m * SLICE_W;
    for (int i = threadIdx.x; i < SLICE_W; i += 1024) {
        int node = nbase + i;
        lcur[i] = (node < N_NODES) ? row_start[node] + 1 : 0;  // +1 skips self-loop slot
    }
    __syncthreads();
    int n = bcursor[b * PAD];
    const int4* sd4 = (const int4*)(stg + (size_t)b * CAP);   // b*CAP*8B is 16B-aligned
    int n4 = n >> 1;
    int lo = m * SLICE_W, hi = lo + SLICE_W;
    for (int base4 = 0; base4 < n4; base4 += 4096) {
        int4 e[4];
        int idx[4];
        #pragma unroll
        for (int j = 0; j < 4; ++j) {
            idx[j] = base4 + j * 1024 + (int)threadIdx.x;
            if (idx[j] < n4) e[j] = sd4[idx[j]];
        }
        #pragma unroll
        for (int j = 0; j < 4; ++j) {
            if (idx[j] < n4) {
                int dl0 = (e[j].x >> 16) & 2047;
                if (dl0 >= lo && dl0 < hi) {
                    int q = atomicAdd(&lcur[dl0 - lo], 1);
                    csr_pack[q] = make_int2(e[j].x & 0xFFFF, e[j].y);
                }
                int dl1 = (e[j].z >> 16) & 2047;
                if (dl1 >= lo && dl1 < hi) {
                    int q = atomicAdd(&lcur[dl1 - lo], 1);
                    csr_pack[q] = make_int2(e[j].z & 0xFFFF, e[j].w);
                }
            }
        }
    }
    if ((n & 1) && threadIdx.x == 0) {   // odd tail edge; only owning slice stores
        int2 e = stg[(size_t)b * CAP + n - 1];
        int dl = (e.x >> 16) & 2047;
        if (dl >= lo && dl < hi) {
            int q = atomicAdd(&lcur[dl - lo], 1);
            csr_pack[q] = make_int2(e.x & 0xFFFF, e.y);
        }
    }
}

// ---- r14-verified: MFMA dual-linear (v_mfma_f32_16x16x16_f16, swapped
// operands, fp32 accumulate; absmax unchanged at 4.88e-4). 43.8 -> <~15us.
template<int K>
__global__ __launch_bounds__(256) void linear_dual_mfma(
        const float* __restrict__ x,
        const float* __restrict__ Wl, const float* __restrict__ bl,
        const float* __restrict__ Wr, const float* __restrict__ br,
        __half* __restrict__ xl, __half* __restrict__ xr) {
    const int KS = K + 4;                    // padded LDS stride (f16 units)
    __shared__ _Float16 Xh[64 * KS];         // 64 nodes x K
    __shared__ _Float16 Wt[128 * KS];        // Wt[c][k]; c<64: Wl, c>=64: Wr
    int t = threadIdx.x;
    int nb = blockIdx.x * 64;
    // stage X (fp32 -> fp16), zero-fill invalid rows
    for (int i = t; i < 64 * (K / 4); i += 256) {
        int n = i / (K / 4), k0 = (i % (K / 4)) * 4;
        float4 v = (nb + n < N_NODES) ? *(const float4*)(x + (size_t)(nb + n) * K + k0)
                                      : make_float4(0.f, 0.f, 0.f, 0.f);
        f16x4 h = {(_Float16)v.x, (_Float16)v.y, (_Float16)v.z, (_Float16)v.w};
        *(f16x4*)&Xh[n * KS + k0] = h;
    }
    // stage W transposed (coalesced reads, scattered u16 LDS writes)
    for (int i = t; i < K * 64; i += 256) {
        int k = i >> 6, c = i & 63;
        Wt[c * KS + k] = (_Float16)Wl[i];
    }
    for (int i = t; i < K * 64; i += 256) {
        int k = i >> 6, c = i & 63;
        Wt[(c + 64) * KS + k] = (_Float16)Wr[i];
    }
    __syncthreads();

    int w = t >> 6, lane = t & 63;
    int np = lane & 15;                      // node within wave tile (B col / D col)
    int g  = lane >> 4;                      // quad index
    int node = nb + w * 16 + np;
    const _Float16* xrow = &Xh[(w * 16 + np) * KS];
    fv4 acc0 = {0.f,0.f,0.f,0.f}, acc1 = {0.f,0.f,0.f,0.f};
    fv4 acc2 = {0.f,0.f,0.f,0.f}, acc3 = {0.f,0.f,0.f,0.f};
    fv4 acc4 = {0.f,0.f,0.f,0.f}, acc5 = {0.f,0.f,0.f,0.f};
    fv4 acc6 = {0.f,0.f,0.f,0.f}, acc7 = {0.f,0.f,0.f,0.f};

#if __has_builtin(__builtin_amdgcn_mfma_f32_16x16x16f16)
    for (int k0 = 0; k0 < K; k0 += 16) {
        f16x4 bf = *(const f16x4*)&xrow[k0 + 4 * g];                 // B = X^T frag
        f16x4 a0 = *(const f16x4*)&Wt[(0 * 16 + np) * KS + k0 + 4 * g];
        f16x4 a1 = *(const f16x4*)&Wt[(1 * 16 + np) * KS + k0 + 4 * g];
        f16x4 a2 = *(const f16x4*)&Wt[(2 * 16 + np) * KS + k0 + 4 * g];
        f16x4 a3 = *(const f16x4*)&Wt[(3 * 16 + np) * KS + k0 + 4 * g];
        f16x4 a4 = *(const f16x4*)&Wt[(4 * 16 + np) * KS + k0 + 4 * g];
        f16x4 a5 = *(const f16x4*)&Wt[(5 * 16 + np) * KS + k0 + 4 * g];
        f16x4 a6 = *(const f16x4*)&Wt[(6 * 16 + np) * KS + k0 + 4 * g];
        f16x4 a7 = *(const f16x4*)&Wt[(7 * 16 + np) * KS + k0 + 4 * g];
        acc0 = __builtin_amdgcn_mfma_f32_16x16x16f16(a0, bf, acc0, 0, 0, 0);
        acc1 = __builtin_amdgcn_mfma_f32_16x16x16f16(a1, bf, acc1, 0, 0, 0);
        acc2 = __builtin_amdgcn_mfma_f32_16x16x16f16(a2, bf, acc2, 0, 0, 0);
        acc3 = __builtin_amdgcn_mfma_f32_16x16x16f16(a3, bf, acc3, 0, 0, 0);
        acc4 = __builtin_amdgcn_mfma_f32_16x16x16f16(a4, bf, acc4, 0, 0, 0);
        acc5 = __builtin_amdgcn_mfma_f32_16x16x16f16(a5, bf, acc5, 0, 0, 0);
        acc6 = __builtin_amdgcn_mfma_f32_16x16x16f16(a6, bf, acc6, 0, 0, 0);
        acc7 = __builtin_amdgcn_mfma_f32_16x16x16f16(a7, bf, acc7, 0, 0, 0);
    }
#else
    // scalar fallback, bit-equivalent lane->element mapping (slow, correct)
    {
        fv4* accs[8] = {&acc0,&acc1,&acc2,&acc3,&acc4,&acc5,&acc6,&acc7};
        for (int ct = 0; ct < 8; ++ct)
            for (int j = 0; j < 4; ++j) {
                float s = 0.f;
                const _Float16* wrow = &Wt[(ct * 16 + 4 * g + j) * KS];
                for (int k = 0; k < K; ++k) s += (float)wrow[k] * (float)xrow[k];
                (*accs[ct])[j] = s;
            }
    }
#endif

    // epilogue: lane holds c = 16*ct + 4*g + j for node `node`
    if (node < N_NODES) {
        #define EMIT(CT, ACC)                                                        \
        {                                                                            \
            const float* bp = ((CT) < 4) ? (bl + (CT) * 16 + 4 * g)                  \
                                         : (br + ((CT) - 4) * 16 + 4 * g);           \
            float4 bv = *(const float4*)bp;                                          \
            f16x4 o = {(_Float16)(ACC[0] + bv.x), (_Float16)(ACC[1] + bv.y),         \
                       (_Float16)(ACC[2] + bv.z), (_Float16)(ACC[3] + bv.w)};        \
            __half* dst = ((CT) < 4)                                                 \
                ? (xl + (size_t)node * D_H + (CT) * 16 + 4 * g)                      \
                : (xr + (size_t)node * D_H + ((CT) - 4) * 16 + 4 * g);               \
            *(f16x4*)dst = o;                                                        \
        }
        EMIT(0, acc0) EMIT(1, acc1) EMIT(2, acc2) EMIT(3, acc3)
        EMIT(4, acc4) EMIT(5, acc5) EMIT(6, acc6) EMIT(7, acc7)
        #undef EMIT
    }
}

// ---- fused GATv2 layer — r9-verified 8-lane-group design. r15 FUSE=1 folds
// mean-pool into the epilogue (h-write/read + pool dispatch deleted; WRITE
// 12.5MB -> 0.5MB verified). r16: the r15 epilogue cost +13us via 2048
// 8-way-contended LDS fp32 atomics per block (bank-conflict 0 -> 37K).
// Now: FAST PATH (wave's 8 nodes same graph & all valid — sorted batch, so
// ~23/24 waves) sums h across groups with 3 shfl_xor steps, then only
// group-0's 8 lanes do LDS atomics (2048 -> 32 per block, conflict-free).
// Boundary/tail waves take the old per-lane path.
template<int FUSE>
__global__ __launch_bounds__(256) void gat_fused(
        const int* __restrict__ row_start, const int2* __restrict__ csr_pack,
        const __half* __restrict__ xl, const __half* __restrict__ xr,
        const float* __restrict__ We, const float* __restrict__ att,
        const float* __restrict__ b, float* __restrict__ out,
        const int* __restrict__ batch, float* __restrict__ pooled,
        float* __restrict__ counts) {
    __shared__ float pl[4][D_H];
    __shared__ int pcnt[4];
    __shared__ int gbase_s;
    if (FUSE) {
        int tt = threadIdx.x;
        if (tt < 4 * D_H) pl[tt >> 6][tt & 63] = 0.f;
        if (tt < 4) pcnt[tt] = 0;
        if (tt == 0) gbase_s = batch[blockIdx.x * 32];   // first node of block
        __syncthreads();
    }
    int lane = threadIdx.x & 63;
    int g = lane >> 3;                      // 8 groups per wave
    int s = lane & 7;                       // 8 lanes per group
    int wid = blockIdx.x * (blockDim.x >> 6) + (threadIdx.x >> 6);
    int node = wid * 8 + g;                 // 32 nodes per 256-thread block
    bool nv = node < N_NODES;
    int nodec = nv ? node : 0;
    int fb = s * 8;                         // 8 dims per lane
    float4 wea = *(const float4*)(We + fb), web = *(const float4*)(We + fb + 4);
    float4 ata = *(const float4*)(att + fb), atb = *(const float4*)(att + fb + 4);
    f16x2 we[4] = {{(_Float16)wea.x, (_Float16)wea.y}, {(_Float16)wea.z, (_Float16)wea.w},
                   {(_Float16)web.x, (_Float16)web.y}, {(_Float16)web.z, (_Float16)web.w}};
    f16x2 at[4] = {{(_Float16)ata.x, (_Float16)ata.y}, {(_Float16)ata.z, (_Float16)ata.w},
                   {(_Float16)atb.x, (_Float16)atb.y}, {(_Float16)atb.z, (_Float16)atb.w}};
    int4 xru = *(const int4*)(xr + (size_t)nodec * D_H + fb);   // 16B, aligned
    f16x2 xr4[4] = {as_h2((unsigned)xru.x), as_h2((unsigned)xru.y),
                    as_h2((unsigned)xru.z), as_h2((unsigned)xru.w)};
    const f16x2 ns = {(_Float16)NEG_SLOPE, (_Float16)NEG_SLOPE};
    int j0 = 0, j1 = 0;
    if (nv) { j0 = row_start[node]; j1 = row_start[node + 1]; }

    float S = 0.f;
    float acc[8] = {0.f, 0.f, 0.f, 0.f, 0.f, 0.f, 0.f, 0.f};

    for (int i0 = j0; i0 < j1; i0 += 4) {   // same trip count across each 8-lane group
        int2 pk[4]; int4 qk[4]; bool vk[4];
        #pragma unroll
        for (int k = 0; k < 4; ++k) {
            vk[k] = (i0 + k) < j1;
            int c = vk[k] ? (i0 + k) : i0;
            pk[k] = csr_pack[c];
        }
        #pragma unroll
        for (int k = 0; k < 4; ++k)
            qk[k] = *(const int4*)(xl + (size_t)pk[k].x * D_H + fb);   // 16B gather
        float t[4];
        #pragma unroll
        for (int k = 0; k < 4; ++k) {
            f16x2 a2 = as_h2((unsigned)pk[k].y);
            f16x2 r0 = as_h2((unsigned)qk[k].x), r1 = as_h2((unsigned)qk[k].y);
            f16x2 r2 = as_h2((unsigned)qk[k].z), r3 = as_h2((unsigned)qk[k].w);
            f16x2 m0 = a2 * we[0] + (r0 + xr4[0]);
            f16x2 m1 = a2 * we[1] + (r1 + xr4[1]);
            f16x2 m2 = a2 * we[2] + (r2 + xr4[2]);
            f16x2 m3 = a2 * we[3] + (r3 + xr4[3]);
            m0 = pk_leaky(m0, ns); m1 = pk_leaky(m1, ns);
            m2 = pk_leaky(m2, ns); m3 = pk_leaky(m3, ns);
            t[k] = fdot2a(m3, at[3], fdot2a(m2, at[2],
                   fdot2a(m1, at[1], fdot2a(m0, at[0], 0.f))));
        }
        #pragma unroll
        for (int off = 1; off <= 4; off <<= 1) {   // reduce within 8-lane group
            t[0] += __shfl_xor(t[0], off);
            t[1] += __shfl_xor(t[1], off);
            t[2] += __shfl_xor(t[2], off);
            t[3] += __shfl_xor(t[3], off);
        }
        #pragma unroll
        for (int k = 0; k < 4; ++k) {
            float z = vk[k] ? __expf(t[k]) : 0.f;
            S += z;
            f16x2 r0 = as_h2((unsigned)qk[k].x), r1 = as_h2((unsigned)qk[k].y);
            f16x2 r2 = as_h2((unsigned)qk[k].z), r3 = as_h2((unsigned)qk[k].w);
            acc[0] = fmaf(z, (float)r0.x, acc[0]);
            acc[1] = fmaf(z, (float)r0.y, acc[1]);
            acc[2] = fmaf(z, (float)r1.x, acc[2]);
            acc[3] = fmaf(z, (float)r1.y, acc[3]);
            acc[4] = fmaf(z, (float)r2.x, acc[4]);
            acc[5] = fmaf(z, (float)r2.y, acc[5]);
            acc[6] = fmaf(z, (float)r3.x, acc[6]);
            acc[7] = fmaf(z, (float)r3.y, acc[7]);
        }
    }

    if (FUSE) {
        // compute h (0 for invalid nodes), then reduce across the 8 groups
        float h[8];
        float4 ba = *(const float4*)(b + fb), bb = *(const float4*)(b + fb + 4);
        float bq[8] = {ba.x, ba.y, ba.z, ba.w, bb.x, bb.y, bb.z, bb.w};
        float inv = 1.f / (S + 1e-16f);
        #pragma unroll
        for (int j = 0; j < 8; ++j) {
            float v = fmaf(acc[j], inv, bq[j]);
            v = v > 0.f ? v : expm1f(v);
            h[j] = nv ? v : 0.f;
        }
        int gi_full = batch[nodec];
        // wave-uniformity check across groups (offsets 8/16/32 flip group bits)
        int gmin = gi_full, gmax = gi_full;
        #pragma unroll
        for (int off = 8; off <= 32; off <<= 1) {
            int a = __shfl_xor(gmin, off), c = __shfl_xor(gmax, off);
            gmin = a < gmin ? a : gmin;
            gmax = c > gmax ? c : gmax;
        }
        int wave_base = (wid & ~0) * 8 - g * 0;          // wave's first node = wid*8 - g*?  (see below)
        // wave's nodes span [wbase, wbase+8): wbase = (blockIdx*4 + waveId)*8
        int wbase = node - g;
        bool wave_full = (wbase + 7) < N_NODES;
        if (gmin == gmax && wave_full) {
            // fast path: in-register cross-group sum, group 0 writes
            #pragma unroll
            for (int j = 0; j < 8; ++j) {
                #pragma unroll
                for (int off = 8; off <= 32; off <<= 1)
                    h[j] += __shfl_xor(h[j], off);
            }
            int gi = gi_full - gbase_s;
            gi = gi < 0 ? 0 : (gi > 3 ? 3 : gi);
            if (g == 0) {
                #pragma unroll
                for (int j = 0; j < 8; ++j) atomicAdd(&pl[gi][fb + j], h[j]);
                if (s == 0) atomicAdd(&pcnt[gi], 8);     // 8 nodes, all same graph
            }
        } else if (nv) {
            // slow path (graph boundary or tail wave): per-lane atomics
            int gi = gi_full - gbase_s;
            gi = gi < 0 ? 0 : (gi > 3 ? 3 : gi);
            #pragma unroll
            for (int j = 0; j < 8; ++j) atomicAdd(&pl[gi][fb + j], h[j]);
            if (s == 0) atomicAdd(&pcnt[gi], 1);
        }
        __syncthreads();
        int tt = threadIdx.x;                 // 256 threads = 4 slots x 64 dims
        int gi2 = tt >> 6, d = tt & 63;
        int c = pcnt[gi2];
        if (c > 0) {
            int gg = gbase_s + gi2;
            atomicAdd(&pooled[gg * D_H + d], pl[gi2][d]);
            if (d == 0) atomicAdd(&counts[gg], (float)c);
        }
    } else if (nv) {
        float4 ba = *(const float4*)(b + fb), bb = *(const float4*)(b + fb + 4);
        float bq[8] = {ba.x, ba.y, ba.z, ba.w, bb.x, bb.y, bb.z, bb.w};
        float inv = 1.f / (S + 1e-16f);
        float h[8];
        #pragma unroll
        for (int j = 0; j < 8; ++j) {
            float v = fmaf(acc[j], inv, bq[j]);
            h[j] = v > 0.f ? v : expm1f(v);
        }
        *(float4*)(out + (size_t)node * D_H + fb)     = make_float4(h[0], h[1], h[2], h[3]);
        *(float4*)(out + (size_t)node * D_H + fb + 4) = make_float4(h[4], h[5], h[6], h[7]);
    }
}

__global__ void classify(const float* __restrict__ pooled, const float* __restrict__ counts,
                         const float* __restrict__ Wc, const float* __restrict__ bc,
                         float* __restrict__ out) {
    int tid = threadIdx.x;             // 640 threads
    int g = tid / N_CLS, c = tid % N_CLS;
    if (g >= N_GRAPHS) return;
    float inv = 1.0f / fmaxf(counts[g], 1.0f);
    float a = bc[c];
    for (int k = 0; k < D_H; ++k)
        a = fmaf(pooled[g * D_H + k] * inv, Wc[k * N_CLS + c], a);
    out[g * N_CLS + c] = a;
}

extern "C" void kernel_launch(void* const* d_in, const int* in_sizes, int n_in,
                              void* d_out, int out_size, void* d_ws, size_t ws_size,
                              hipStream_t stream) {
    const float* x     = (const float*)d_in[0];
    const int*   ei    = (const int*)d_in[1];
    const float* eattr = (const float*)d_in[2];
    const int*   batch = (const int*)d_in[3];
    const float *Wl1 = (const float*)d_in[4],  *bl1 = (const float*)d_in[5];
    const float *Wr1 = (const float*)d_in[6],  *br1 = (const float*)d_in[7];
    const float *We1 = (const float*)d_in[8],  *att1 = (const float*)d_in[9];
    const float *b1  = (const float*)d_in[10];
    const float *Wl2 = (const float*)d_in[11], *bl2 = (const float*)d_in[12];
    const float *Wr2 = (const float*)d_in[13], *br2 = (const float*)d_in[14];
    const float *We2 = (const float*)d_in[15], *att2 = (const float*)d_in[16];
    const float *b2  = (const float*)d_in[17];
    const float *Wc  = (const float*)d_in[18], *bc = (const float*)d_in[19];
    float* out = (float*)d_out;

    const int* src = ei;
    const int* dst = ei + N_EDGES;

    // workspace layout. stg (int2, 15.36 MB) is dead after scatter; xl/xr (fp16,
    // 6.4 MB each) + h (fp32, 12.8 MB) = 25.6 MB alias its region. csr_pack kept
    // at the old 30.72 MB offset so it stays clear of xl/xr/h.
    char* base = (char*)d_ws;
    int2*  stg     = (int2*)base;                       // NB*CAP*8B = 15.36 MB
    __half* xl     = (__half*)base;                     // N*64 fp16 (6.4 MB)
    __half* xr     = xl + (size_t)N_NODES * D_H;        // N*64 fp16
    float* h       = (float*)(xr + (size_t)N_NODES * D_H); // N*64 fp32 (12.8 MB)
    int2*  csr_pack = (int2*)(base + (size_t)NB * CAP * 16); // E2 (8B) = 13.2 MB
    int*   row_start = (int*)(csr_pack + E2);           // N+1
    int*   cnt     = row_start + N_NODES + 1;           // N
    float* esum    = (float*)(cnt + N_NODES);           // 32 lines (32*PAD floats)
    int*   bcursor = (int*)(esum + 32 * PAD);           // NB lines (NB*PAD ints)
    int*   cursor  = bcursor + NB * PAD;                // N
    int*   partial = cursor + N_NODES;                  // NBLK
    float* pooled  = (float*)(partial + NBLK);          // 64*64
    float* counts  = pooled + N_GRAPHS * D_H;           // 64

    int gat_blocks = (N_NODES + 31) / 32;               // 32 nodes per 256-thr block
    int mfma_blocks = (N_NODES + 63) / 64;              // 64 nodes per block

    hipMemsetAsync(cnt, 0, (N_NODES + 32 * PAD + NB * PAD) * sizeof(int), stream);
    hipMemsetAsync(pooled, 0, (N_GRAPHS * D_H + N_GRAPHS) * sizeof(float), stream);

    // ---- CSR build: stage -> LDS hist -> scan -> slice-scatter ----
    bucket_stage<<<(N_EDGES / EPT + 255) / 256, 256, 0, stream>>>(
        src, dst, eattr, esum, bcursor, stg);
    hist_bucket<<<NB * HBB, 256, 0, stream>>>(stg, bcursor, cnt);
    scan_block<<<NBLK, SCAN_BS, 0, stream>>>(cnt, row_start, partial);
    add_offsets<<<NBLK, SCAN_BS, 0, stream>>>(row_start, partial, cursor, esum, csr_pack);
    scatter_slice<<<SLICES * 32, 1024, 0, stream>>>(stg, bcursor, row_start, csr_pack);

    // ---------------- layer 1 ----------------
    linear_dual_mfma<D_IN><<<mfma_blocks, 256, 0, stream>>>(x, Wl1, bl1, Wr1, br1, xl, xr);
    gat_fused<0><<<gat_blocks, 256, 0, stream>>>(row_start, csr_pack, xl, xr,
                                                 We1, att1, b1, h, batch, pooled, counts);

    // ---------------- layer 2 ----------------
    linear_dual_mfma<D_H><<<mfma_blocks, 256, 0, stream>>>(h, Wl2, bl2, Wr2, br2, xl, xr);
    gat_fused<1><<<gat_blocks, 256, 0, stream>>>(row_start, csr_pack, xl, xr,
                                                 We2, att2, b2, h, batch, pooled, counts);

    // ---------------- pool folded into gat layer 2; classify only ----------------
    classify<<<1, 640, 0, stream>>>(pooled, counts, Wc, bc, out);
}